// Round 11
// baseline (305.494 us; speedup 1.0000x reference)
//
#include <hip/hip_runtime.h>
#include <cstdint>
#include <cstddef>

// ---------------- types ----------------
typedef _Float16 half8 __attribute__((ext_vector_type(8)));
typedef _Float16 half4 __attribute__((ext_vector_type(4)));
typedef float f32x4 __attribute__((ext_vector_type(4)));

#define DI __device__ __forceinline__

// global -> LDS async copy, 16B per lane. LDS dest must be WAVE-UNIFORM; HW adds lane*16.
DI void gld_lds16(void* sp, const void* gp) {
  __builtin_amdgcn_global_load_lds(
      (const __attribute__((address_space(1))) void*)gp,
      (__attribute__((address_space(3))) void*)sp, 16, 0, 0);
}

template <int N>
DI void vmwait() { asm volatile("s_waitcnt vmcnt(%0)" :: "n"(N) : "memory"); }

// raw barrier (no vmcnt drain) with compiler-level memory fences on both sides
DI void barrier_raw() {
  asm volatile("" ::: "memory");
  __builtin_amdgcn_s_barrier();
  asm volatile("" ::: "memory");
}

// ---------------- merged weight/activation prep (1 launch) -----------------------
__global__ __launch_bounds__(256) void prep(const float* __restrict__ hs,
                                            const float* __restrict__ Wq,
                                            const float* __restrict__ Wk,
                                            const float* __restrict__ Wv,
                                            const float* __restrict__ Wo,
                                            _Float16* __restrict__ Xh,
                                            _Float16* __restrict__ Wqkvt,
                                            _Float16* __restrict__ Wot) {
  const int bid = blockIdx.x;
  if (bid >= 12288) {
    const int i = (bid - 12288) * 256 + threadIdx.x;
    const float4* p = (const float4*)hs + (size_t)i * 2;
    const float4 a = p[0], b = p[1];
    half8 h;
    h[0] = (_Float16)a.x; h[1] = (_Float16)a.y; h[2] = (_Float16)a.z; h[3] = (_Float16)a.w;
    h[4] = (_Float16)b.x; h[5] = (_Float16)b.y; h[6] = (_Float16)b.z; h[7] = (_Float16)b.w;
    *(half8*)(Xh + (size_t)i * 8) = h;
    return;
  }
  const float* in;
  _Float16* outp;
  int C, t;
  if (bid < 4096)      { in = Wq; outp = Wqkvt;                        C = 2048; t = bid; }
  else if (bid < 6144) { in = Wk; outp = Wqkvt + (size_t)2048 * 2048;  C = 1024; t = bid - 4096; }
  else if (bid < 8192) { in = Wv; outp = Wqkvt + (size_t)3072 * 2048;  C = 1024; t = bid - 6144; }
  else                 { in = Wo; outp = Wot;                          C = 2048; t = bid - 8192; }
  __shared__ float tl[32][33];
  const int tx = threadIdx.x & 31, ty = threadIdx.x >> 5;
  const int ctiles = C >> 5;
  const int tc = t % ctiles, tr = t / ctiles;
  const int r0 = tr * 32, c0 = tc * 32;
#pragma unroll
  for (int i = 0; i < 4; i++)
    tl[ty + 8 * i][tx] = in[(size_t)(r0 + ty + 8 * i) * C + c0 + tx];
  __syncthreads();
#pragma unroll
  for (int i = 0; i < 4; i++) {
    const int rr = ty + 8 * i;
    outp[(size_t)(c0 + rr) * 2048 + r0 + tx] = (_Float16)tl[tx][rr];
  }
}

// ---------------- 256x256 8-phase GEMM (m201-template port, f16) -------------------
// Verified R9: QKV 2048-K at ~1.05+ PF. Schedule comments in R9 journal.
#define QPHASE(Q, STAGE, VMW)                                                  \
  {                                                                            \
    half8 afr[2][2];                                                           \
    _Pragma("unroll") for (int j = 0; j < 2; j++)                              \
      _Pragma("unroll") for (int ks = 0; ks < 2; ks++) {                       \
        const int arow = wm * 128 + ((Q) * 2 + j) * 16 + lo;                   \
        afr[j][ks] =                                                           \
            *(const half8*)&sA[sa][arow * 64 + (((ks * 4 + hi) ^ lo7) << 3)];  \
      }                                                                        \
    STAGE;                                                                     \
    VMW;                                                                       \
    barrier_raw();                                                             \
    asm volatile("s_waitcnt lgkmcnt(0)" ::: "memory");                         \
    __builtin_amdgcn_sched_barrier(0);                                         \
    __builtin_amdgcn_s_setprio(1);                                             \
    _Pragma("unroll") for (int j = 0; j < 2; j++)                              \
      _Pragma("unroll") for (int nf = 0; nf < 4; nf++)                         \
        _Pragma("unroll") for (int ks = 0; ks < 2; ks++)                       \
          acc[(Q) * 2 + j][nf] = __builtin_amdgcn_mfma_f32_16x16x32_f16(       \
              afr[j][ks], bfr[nf][ks], acc[(Q) * 2 + j][nf], 0, 0, 0);         \
    __builtin_amdgcn_s_setprio(0);                                             \
    barrier_raw();                                                             \
  }

__global__ __launch_bounds__(512, 2) void gemm256(const _Float16* __restrict__ A,
                                                  const _Float16* __restrict__ Bt,
                                                  float* __restrict__ C,
                                                  int M, int N, int K) {
  __shared__ _Float16 sA[3][16384];  // 3 x 32KB (256 rows x 64 k, swizzled)
  __shared__ _Float16 sB[2][16384];  // 2 x 32KB
  const int tid = threadIdx.x, w = tid >> 6, l = tid & 63, lo = l & 15, hi = l >> 4;
  const int lo7 = lo & 7;
  const int wm = w >> 2, wn = w & 3;
  const int nbn = N >> 8;
  const int nwg = gridDim.x;
  int bid = blockIdx.x;
  bid = (bid & 7) * (nwg >> 3) + (bid >> 3);  // bijective XCD remap (nwg % 8 == 0)
  const int bm0 = (bid / nbn) << 8, bn0 = (bid % nbn) << 8;
  const int cswz = ((tid & 7) ^ ((tid >> 3) & 7)) << 3;  // staged element col (inv-swz)
  const int NT = K >> 6;

  auto stageA = [&](int kt, int slot, int i0) {
#pragma unroll
    for (int ii = 0; ii < 2; ++ii) {
      const int i = i0 + ii;
      gld_lds16(&sA[slot][i * 4096 + (w << 9)],
                A + (size_t)(bm0 + i * 64 + (tid >> 3)) * K + kt * 64 + cswz);
    }
  };
  auto stageB = [&](int kt, int slot, int i0) {
#pragma unroll
    for (int ii = 0; ii < 2; ++ii) {
      const int i = i0 + ii;
      gld_lds16(&sB[slot][i * 4096 + (w << 9)],
                Bt + (size_t)(bn0 + i * 64 + (tid >> 3)) * K + kt * 64 + cswz);
    }
  };

  f32x4 acc[8][4];
#pragma unroll
  for (int mf = 0; mf < 8; mf++)
#pragma unroll
    for (int nf = 0; nf < 4; nf++)
#pragma unroll
      for (int r = 0; r < 4; r++) acc[mf][nf][r] = 0.0f;

  stageA(0, 0, 0); stageA(0, 0, 2);
  stageA(1, 1, 0); stageA(1, 1, 2);
  stageB(0, 0, 0); stageB(0, 0, 2);
  vmwait<0>();
  barrier_raw();

  int sa = 0, sa2 = 2;
#pragma unroll 1
  for (int t = 0; t < NT; ++t) {
    const int sb = t & 1, sb1 = sb ^ 1;
    half8 bfr[4][2];
#pragma unroll
    for (int nf = 0; nf < 4; nf++)
#pragma unroll
      for (int ks = 0; ks < 2; ks++) {
        const int brow = wn * 64 + nf * 16 + lo;
        bfr[nf][ks] = *(const half8*)&sB[sb][brow * 64 + (((ks * 4 + hi) ^ lo7) << 3)];
      }
    QPHASE(0, if (t + 1 < NT) stageB(t + 1, sb1, 0), )
    QPHASE(1, if (t + 1 < NT) stageB(t + 1, sb1, 2), )
    QPHASE(2, if (t + 2 < NT) stageA(t + 2, sa2, 0), )
    QPHASE(3, if (t + 2 < NT) stageA(t + 2, sa2, 2),
           if (t + 2 < NT) { vmwait<4>(); } else { vmwait<0>(); })
    sa = (sa == 2) ? 0 : sa + 1;
    sa2 = (sa2 == 2) ? 0 : sa2 + 1;
  }

  // C/D layout: col = lane&15, row = (lane>>4)*4 + reg  [m89/m91 verified]
#pragma unroll
  for (int mf = 0; mf < 8; mf++)
#pragma unroll
    for (int nf = 0; nf < 4; nf++)
#pragma unroll
      for (int r = 0; r < 4; r++)
        C[(size_t)(bm0 + wm * 128 + mf * 16 + hi * 4 + r) * N +
          (bn0 + wn * 64 + nf * 16 + lo)] = acc[mf][nf][r];
}

// ---------------- GEMM: proven R5 2-phase structure (used for out-projection) ------
template <int BM, bool F16OUT>
__global__ __launch_bounds__(256) void gemm_bt(const _Float16* __restrict__ A,
                                               const _Float16* __restrict__ Bt,
                                               void* __restrict__ Cv,
                                               int M, int N, int K) {
  constexpr int MF = BM / 32;   // per-wave m-frags
  constexpr int LA = BM / 64;   // per-wave A staging instrs per K-step
  __shared__ _Float16 sA[2][BM * 32];
  __shared__ _Float16 sB[2][128 * 32];
  const int tid = threadIdx.x;
  const int w = tid >> 6, l = tid & 63, lo = l & 15, hi = l >> 4;
  const int gx = gridDim.x, nwg = gx * gridDim.y;
  int bid = blockIdx.y * gx + blockIdx.x;
  bid = (bid & 7) * (nwg >> 3) + (bid >> 3);
  const int bn0 = (bid % gx) * 128, bm0 = (bid / gx) * BM;
  const int wm = w >> 1, wn = w & 1;
  const int srow = l >> 2;
  const int csel = ((l & 3) ^ ((l >> 3) & 3)) * 8;
  const int kswz = (hi ^ ((lo >> 1) & 3)) * 8;

  f32x4 acc[MF][4];
#pragma unroll
  for (int mi = 0; mi < MF; mi++)
#pragma unroll
    for (int ni = 0; ni < 4; ni++)
#pragma unroll
      for (int r = 0; r < 4; r++) acc[mi][ni][r] = 0.0f;

  auto stage = [&](int bi, int kt) {
#pragma unroll
    for (int i = 0; i < LA; ++i) {
      const int j = LA * w + i;
      gld_lds16(&sA[bi][j * 512],
                A + (size_t)(bm0 + j * 16 + srow) * K + (size_t)kt * 32 + csel);
    }
#pragma unroll
    for (int i = 0; i < 2; ++i) {
      const int j = 2 * w + i;
      gld_lds16(&sB[bi][j * 512],
                Bt + (size_t)(bn0 + j * 16 + srow) * K + (size_t)kt * 32 + csel);
    }
  };

  stage(0, 0);
  __syncthreads();
  const int KT = K >> 5;
#pragma unroll 1
  for (int kt = 0; kt < KT; ++kt) {
    const int cur = kt & 1;
    if (kt + 1 < KT) stage(cur ^ 1, kt + 1);
    half8 a[MF], b[4];
#pragma unroll
    for (int mi = 0; mi < MF; mi++)
      a[mi] = *(const half8*)&sA[cur][(wm * (BM / 2) + mi * 16 + lo) * 32 + kswz];
#pragma unroll
    for (int ni = 0; ni < 4; ni++)
      b[ni] = *(const half8*)&sB[cur][(wn * 64 + ni * 16 + lo) * 32 + kswz];
#pragma unroll
    for (int mi = 0; mi < MF; mi++)
#pragma unroll
      for (int ni = 0; ni < 4; ni++)
        acc[mi][ni] = __builtin_amdgcn_mfma_f32_16x16x32_f16(a[mi], b[ni], acc[mi][ni], 0, 0, 0);
    __syncthreads();
  }

#pragma unroll
  for (int mi = 0; mi < MF; mi++)
#pragma unroll
    for (int ni = 0; ni < 4; ni++)
#pragma unroll
      for (int r = 0; r < 4; r++) {
        const size_t idx = (size_t)(bm0 + wm * (BM / 2) + mi * 16 + hi * 4 + r) * N +
                           (bn0 + wn * 64 + ni * 16 + lo);
        if constexpr (F16OUT) ((_Float16*)Cv)[idx] = (_Float16)acc[mi][ni][r];
        else                  ((float*)Cv)[idx] = acc[mi][ni][r];
      }
}

// ---------------- fused RMSNorm+RoPE (Q,K) + V transpose, one launch --------------
__global__ __launch_bounds__(256) void post(const float* __restrict__ QKV,
                                            const int* __restrict__ pos,
                                            const float* __restrict__ qw,
                                            const float* __restrict__ kw,
                                            _Float16* __restrict__ Qb,
                                            _Float16* __restrict__ Kb,
                                            _Float16* __restrict__ Vt) {
  if (blockIdx.x >= 24576) {
    __shared__ float tt[32][33];
    const int g = blockIdx.x - 24576;
    const int tx = threadIdx.x & 31, ty = threadIdx.x >> 5;
    const int dt = g & 3;
    const int st = (g >> 2) & 63;
    const int bh = g >> 8;
    const float* src = QKV + (size_t)((bh >> 3) * 2048 + st * 32) * 4096 +
                       3072 + (bh & 7) * 128 + dt * 32;
#pragma unroll
    for (int i = 0; i < 4; i++)
      tt[ty + 8 * i][tx] = src[(size_t)(ty + 8 * i) * 4096 + tx];
    __syncthreads();
    _Float16* dst = Vt + ((size_t)bh * 128 + dt * 32) * 2048 + st * 32;
#pragma unroll
    for (int i = 0; i < 4; i++) {
      const int rr = ty + 8 * i;
      dst[(size_t)rr * 2048 + tx] = (_Float16)tt[tx][rr];
    }
    return;
  }
  const int w = threadIdx.x >> 6, l = threadIdx.x & 63;
  const int wv = blockIdx.x * 4 + w;
  const int t = wv / 24, hh = wv - t * 24;
  const int b = t >> 11, s = t & 2047;
  const bool isq = hh < 16;
  const int col = isq ? hh * 128 : 2048 + (hh - 16) * 128;
  const float* x = QKV + (size_t)t * 4096 + col;
  const float x1 = x[l], x2 = x[l + 64];
  float ss = x1 * x1 + x2 * x2;
  ss += __shfl_xor(ss, 32); ss += __shfl_xor(ss, 16); ss += __shfl_xor(ss, 8);
  ss += __shfl_xor(ss, 4);  ss += __shfl_xor(ss, 2);  ss += __shfl_xor(ss, 1);
  const float rn = rsqrtf(ss * 0.0078125f + 1e-6f);
  const float* wt = isq ? qw : kw;
  const float n1 = x1 * rn * wt[l], n2 = x2 * rn * wt[l + 64];
  const float ang = (float)pos[s] * exp2f((float)l * -0.2076205059304601f);
  float sa, ca;
  sincosf(ang, &sa, &ca);
  const float qs = isq ? 0.12751731f : 1.0f;  // SCALE * log2(e), Q only
  const float o1 = (n1 * ca - n2 * sa) * qs;
  const float o2 = (n2 * ca + n1 * sa) * qs;
  _Float16* dst = isq ? Qb + (((size_t)b * 16 + hh) * 2048 + s) * 128
                      : Kb + (((size_t)b * 8 + (hh - 16)) * 2048 + s) * 128;
  dst[l] = (_Float16)o1;
  dst[l + 64] = (_Float16)o2;
}

// ---------------- causal GQA flash attention ---------------------------------------
// Swapped QK^T + in-lane softmax (R3). This round: V staging dropped (V per head is
// L2-resident; direct global reads into regs, issued at loop top so softmax hides
// L2 latency). LDS 74 -> 42 KB => 3 blocks/CU (12 waves) vs 2. launch_bounds(256,3)
// caps VGPR at 170 for the 3-wave/SIMD target.
__global__ __launch_bounds__(256, 3) void attn_fwd(const _Float16* __restrict__ Q,
                                                   const _Float16* __restrict__ K,
                                                   const _Float16* __restrict__ Vt,
                                                   _Float16* __restrict__ AO) {
  __shared__ _Float16 sK[2][64 * 128];   // 16 KB per buffer
  __shared__ _Float16 P[4][16 * 80];     // per-wave P tile, padded stride 80
  const int tid = threadIdx.x, w = tid >> 6, l = tid & 63, lo = l & 15, hi = l >> 4;
  const int qt = 31 - (blockIdx.x >> 5);  // heavy-first launch order
  const int hq = blockIdx.x & 15;
  const int b = (blockIdx.x >> 4) & 1;
  const int hk = hq >> 1, q0 = qt * 64;
  const _Float16* Qh = Q + ((size_t)(b * 16 + hq) * 2048) * 128;
  const _Float16* Kh = K + ((size_t)(b * 8 + hk) * 2048) * 128;
  const _Float16* Vh = Vt + ((size_t)(b * 8 + hk) * 128) * 2048;
  const int qw0 = q0 + w * 16;

  auto stageK = [&](int bi, int kv0) {
#pragma unroll
    for (int i = 0; i < 4; ++i) {
      const int inst = w * 4 + i;
      const int r = inst * 4 + (l >> 4);
      const int cb = ((l & 15) * 16) ^ ((r & 7) << 4);
      gld_lds16(&sK[bi][inst * 512],
                (const char*)Kh + (size_t)(kv0 + r) * 256 + cb);
    }
  };

  half8 aq[4];
#pragma unroll
  for (int kc = 0; kc < 4; kc++)
    aq[kc] = *(const half8*)(Qh + (size_t)(qw0 + lo) * 128 + kc * 32 + hi * 8);

  f32x4 o[8];
#pragma unroll
  for (int dn = 0; dn < 8; dn++)
#pragma unroll
    for (int r = 0; r < 4; r++) o[dn][r] = 0.0f;
  float mrow = -1e30f, lrow = 0.0f;  // per-lane: q row = qw0 + lo

  const int nt = qt + 1;
  stageK(0, 0);
  __syncthreads();
#pragma unroll 1
  for (int kt = 0; kt < nt; ++kt) {
    const int kv0 = kt * 64;
    const int cur = kt & 1;
    // ---- V fragment loads (global, L2-resident), issued FIRST so the counted
    // vmcnt before their PV use does not force the stageK prefetch to drain ----
    half8 bv[8][2];
#pragma unroll
    for (int dn = 0; dn < 8; dn++) {
      const _Float16* vp = Vh + (size_t)(dn * 16 + lo) * 2048 + kv0 + hi * 8;
      bv[dn][0] = *(const half8*)vp;
      bv[dn][1] = *(const half8*)(vp + 32);
    }
    if (kt + 1 < nt) stageK(cur ^ 1, kv0 + 64);  // K prefetch overlaps compute
    const char* kb = (const char*)sK[cur];
    // ---- S^T = K Q^T (swapped: M=kv64, N=q16, K=d128) ----
    f32x4 s[4];
#pragma unroll
    for (int ns = 0; ns < 4; ns++) {
#pragma unroll
      for (int r = 0; r < 4; r++) s[ns][r] = 0.0f;
      const int krow = ns * 16 + lo;
#pragma unroll
      for (int kc = 0; kc < 4; kc++) {
        half8 bk = *(const half8*)(kb + krow * 256 +
                                   ((kc * 64 + hi * 16) ^ ((krow & 7) << 4)));
        s[ns] = __builtin_amdgcn_mfma_f32_16x16x32_f16(bk, aq[kc], s[ns], 0, 0, 0);
      }
    }
    // ---- causal mask: only the diagonal tile has masked entries ----
    if (kt == nt - 1) {
#pragma unroll
      for (int ns = 0; ns < 4; ns++) {
        const int kv = kv0 + ns * 16 + hi * 4;
#pragma unroll
        for (int r = 0; r < 4; r++)
          if (kv + r > qw0 + lo) s[ns][r] = -1e30f;
      }
    }
    // ---- in-lane row max (16 vals) + cross-hi reduce (2 shuffles) ----
    float tmax = s[0][0];
#pragma unroll
    for (int ns = 0; ns < 4; ns++)
#pragma unroll
      for (int r = 0; r < 4; r++) tmax = fmaxf(tmax, s[ns][r]);
    tmax = fmaxf(tmax, __shfl_xor(tmax, 16));
    tmax = fmaxf(tmax, __shfl_xor(tmax, 32));
    // ---- defer-max (T13): skip rescale when max growth <= 8 (log2 units) ----
    if (!__all(tmax <= mrow + 8.0f)) {
      const float mn = fmaxf(mrow, tmax);
      const float corr = exp2f(mrow - mn);
      mrow = mn;
      lrow *= corr;
      float c4[4];
#pragma unroll
      for (int r = 0; r < 4; r++) c4[r] = __shfl(corr, hi * 4 + r, 16);
#pragma unroll
      for (int dn = 0; dn < 8; dn++)
#pragma unroll
        for (int r = 0; r < 4; r++) o[dn][r] *= c4[r];
    }
    // ---- P = exp2(S - m), scalar cvt (compiler packs), ds_write_b64 ----
    float psum = 0.0f;
#pragma unroll
    for (int ns = 0; ns < 4; ns++) {
      half4 pk;
#pragma unroll
      for (int r = 0; r < 4; r++) {
        const float p = exp2f(s[ns][r] - mrow);
        psum += p;
        pk[r] = (_Float16)p;
      }
      *(half4*)&P[w][lo * 80 + ns * 16 + hi * 4] = pk;
    }
    psum += __shfl_xor(psum, 16);
    psum += __shfl_xor(psum, 32);
    lrow += psum;
    asm volatile("s_waitcnt lgkmcnt(0)" ::: "memory");
    half8 ap0 = *(const half8*)&P[w][lo * 80 + hi * 8];
    half8 ap1 = *(const half8*)&P[w][lo * 80 + 32 + hi * 8];
    // ---- O += P V (M=q16, N=d128, K=kv64), V from registers ----
#pragma unroll
    for (int dn = 0; dn < 8; dn++) {
      o[dn] = __builtin_amdgcn_mfma_f32_16x16x32_f16(ap0, bv[dn][0], o[dn], 0, 0, 0);
      o[dn] = __builtin_amdgcn_mfma_f32_16x16x32_f16(ap1, bv[dn][1], o[dn], 0, 0, 0);
    }
    __syncthreads();  // drains vmcnt(0): K prefetch landed; sK[cur] reads done
  }

  const float inv = 1.0f / lrow;
  float i4[4];
#pragma unroll
  for (int r = 0; r < 4; r++) i4[r] = __shfl(inv, hi * 4 + r, 16);
  const size_t tok = (size_t)b * 2048 + qw0;
#pragma unroll
  for (int dn = 0; dn < 8; dn++)
#pragma unroll
    for (int r = 0; r < 4; r++)
      AO[(tok + hi * 4 + r) * 2048 + hq * 128 + dn * 16 + lo] = (_Float16)(o[dn][r] * i4[r]);
}

// ---------------- launch ----------------
extern "C" void kernel_launch(void* const* d_in, const int* in_sizes, int n_in,
                              void* d_out, int out_size, void* d_ws, size_t ws_size,
                              hipStream_t stream) {
  (void)in_sizes; (void)n_in; (void)out_size; (void)ws_size;
  const float* hs  = (const float*)d_in[0];
  const int*   pos = (const int*)d_in[1];
  const float* Wq  = (const float*)d_in[2];
  const float* Wk  = (const float*)d_in[3];
  const float* Wv  = (const float*)d_in[4];
  const float* Wo  = (const float*)d_in[5];
  const float* qnw = (const float*)d_in[6];
  const float* knw = (const float*)d_in[7];
  float* out = (float*)d_out;

  char* ws = (char*)d_ws;
  size_t off = 0;
  auto take = [&](size_t bytes) -> void* {
    void* p = ws + off;
    off += (bytes + 255) & ~(size_t)255;
    return p;
  };
  _Float16* Xh    = (_Float16*)take((size_t)4096 * 2048 * 2);   // hidden f16
  _Float16* Wqkvt = (_Float16*)take((size_t)4096 * 2048 * 2);   // packed [Wq;Wk;Wv]^T
  _Float16* Wot   = (_Float16*)take((size_t)2048 * 2048 * 2);   // Wo^T
  float*    QKV   = (float*)take((size_t)4096 * 4096 * 4);      // projection out f32
  _Float16* Qb    = (_Float16*)take((size_t)2 * 16 * 2048 * 128 * 2);
  _Float16* Kb    = (_Float16*)take((size_t)2 * 8 * 2048 * 128 * 2);
  _Float16* Vt    = (_Float16*)take((size_t)2 * 8 * 128 * 2048 * 2);
  _Float16* AO    = (_Float16*)take((size_t)4096 * 2048 * 2);   // attention out f16

  prep<<<16384, 256, 0, stream>>>(hs, Wq, Wk, Wv, Wo, Xh, Wqkvt, Wot);
  gemm256<<<256, 512, 0, stream>>>(Xh, Wqkvt, QKV, 4096, 4096, 2048);
  post<<<28672, 256, 0, stream>>>(QKV, pos, qnw, knw, Qb, Kb, Vt);
  attn_fwd<<<1024, 256, 0, stream>>>(Qb, Kb, Vt, AO);
  gemm_bt<64, false><<<dim3(16, 64), 256, 0, stream>>>(AO, Wot, out, 4096, 2048, 2048);
}

// Round 12
// 248.606 us; speedup vs baseline: 1.2288x; 1.2288x over previous
//
#include <hip/hip_runtime.h>
#include <cstdint>
#include <cstddef>

// ---------------- types ----------------
typedef _Float16 half8 __attribute__((ext_vector_type(8)));
typedef _Float16 half4 __attribute__((ext_vector_type(4)));
typedef float f32x4 __attribute__((ext_vector_type(4)));

#define DI __device__ __forceinline__

// global -> LDS async copy, 16B per lane. LDS dest must be WAVE-UNIFORM; HW adds lane*16.
DI void gld_lds16(void* sp, const void* gp) {
  __builtin_amdgcn_global_load_lds(
      (const __attribute__((address_space(1))) void*)gp,
      (__attribute__((address_space(3))) void*)sp, 16, 0, 0);
}

template <int N>
DI void vmwait() { asm volatile("s_waitcnt vmcnt(%0)" :: "n"(N) : "memory"); }

// raw barrier (no vmcnt drain) with compiler-level memory fences on both sides
DI void barrier_raw() {
  asm volatile("" ::: "memory");
  __builtin_amdgcn_s_barrier();
  asm volatile("" ::: "memory");
}

// ---------------- merged weight/activation prep (1 launch) -----------------------
__global__ __launch_bounds__(256) void prep(const float* __restrict__ hs,
                                            const float* __restrict__ Wq,
                                            const float* __restrict__ Wk,
                                            const float* __restrict__ Wv,
                                            const float* __restrict__ Wo,
                                            _Float16* __restrict__ Xh,
                                            _Float16* __restrict__ Wqkvt,
                                            _Float16* __restrict__ Wot) {
  const int bid = blockIdx.x;
  if (bid >= 12288) {
    const int i = (bid - 12288) * 256 + threadIdx.x;
    const float4* p = (const float4*)hs + (size_t)i * 2;
    const float4 a = p[0], b = p[1];
    half8 h;
    h[0] = (_Float16)a.x; h[1] = (_Float16)a.y; h[2] = (_Float16)a.z; h[3] = (_Float16)a.w;
    h[4] = (_Float16)b.x; h[5] = (_Float16)b.y; h[6] = (_Float16)b.z; h[7] = (_Float16)b.w;
    *(half8*)(Xh + (size_t)i * 8) = h;
    return;
  }
  const float* in;
  _Float16* outp;
  int C, t;
  if (bid < 4096)      { in = Wq; outp = Wqkvt;                        C = 2048; t = bid; }
  else if (bid < 6144) { in = Wk; outp = Wqkvt + (size_t)2048 * 2048;  C = 1024; t = bid - 4096; }
  else if (bid < 8192) { in = Wv; outp = Wqkvt + (size_t)3072 * 2048;  C = 1024; t = bid - 6144; }
  else                 { in = Wo; outp = Wot;                          C = 2048; t = bid - 8192; }
  __shared__ float tl[32][33];
  const int tx = threadIdx.x & 31, ty = threadIdx.x >> 5;
  const int ctiles = C >> 5;
  const int tc = t % ctiles, tr = t / ctiles;
  const int r0 = tr * 32, c0 = tc * 32;
#pragma unroll
  for (int i = 0; i < 4; i++)
    tl[ty + 8 * i][tx] = in[(size_t)(r0 + ty + 8 * i) * C + c0 + tx];
  __syncthreads();
#pragma unroll
  for (int i = 0; i < 4; i++) {
    const int rr = ty + 8 * i;
    outp[(size_t)(c0 + rr) * 2048 + r0 + tx] = (_Float16)tl[tx][rr];
  }
}

// ---------------- 256x256 8-phase GEMM (m201-template port, f16) -------------------
// Verified R9: QKV 2048-K at ~1.05+ PF. Schedule comments in R9 journal.
#define QPHASE(Q, STAGE, VMW)                                                  \
  {                                                                            \
    half8 afr[2][2];                                                           \
    _Pragma("unroll") for (int j = 0; j < 2; j++)                              \
      _Pragma("unroll") for (int ks = 0; ks < 2; ks++) {                       \
        const int arow = wm * 128 + ((Q) * 2 + j) * 16 + lo;                   \
        afr[j][ks] =                                                           \
            *(const half8*)&sA[sa][arow * 64 + (((ks * 4 + hi) ^ lo7) << 3)];  \
      }                                                                        \
    STAGE;                                                                     \
    VMW;                                                                       \
    barrier_raw();                                                             \
    asm volatile("s_waitcnt lgkmcnt(0)" ::: "memory");                         \
    __builtin_amdgcn_sched_barrier(0);                                         \
    __builtin_amdgcn_s_setprio(1);                                             \
    _Pragma("unroll") for (int j = 0; j < 2; j++)                              \
      _Pragma("unroll") for (int nf = 0; nf < 4; nf++)                         \
        _Pragma("unroll") for (int ks = 0; ks < 2; ks++)                       \
          acc[(Q) * 2 + j][nf] = __builtin_amdgcn_mfma_f32_16x16x32_f16(       \
              afr[j][ks], bfr[nf][ks], acc[(Q) * 2 + j][nf], 0, 0, 0);         \
    __builtin_amdgcn_s_setprio(0);                                             \
    barrier_raw();                                                             \
  }

__global__ __launch_bounds__(512, 2) void gemm256(const _Float16* __restrict__ A,
                                                  const _Float16* __restrict__ Bt,
                                                  float* __restrict__ C,
                                                  int M, int N, int K) {
  __shared__ _Float16 sA[3][16384];  // 3 x 32KB (256 rows x 64 k, swizzled)
  __shared__ _Float16 sB[2][16384];  // 2 x 32KB
  const int tid = threadIdx.x, w = tid >> 6, l = tid & 63, lo = l & 15, hi = l >> 4;
  const int lo7 = lo & 7;
  const int wm = w >> 2, wn = w & 3;
  const int nbn = N >> 8;
  const int nwg = gridDim.x;
  int bid = blockIdx.x;
  bid = (bid & 7) * (nwg >> 3) + (bid >> 3);  // bijective XCD remap (nwg % 8 == 0)
  const int bm0 = (bid / nbn) << 8, bn0 = (bid % nbn) << 8;
  const int cswz = ((tid & 7) ^ ((tid >> 3) & 7)) << 3;  // staged element col (inv-swz)
  const int NT = K >> 6;

  auto stageA = [&](int kt, int slot, int i0) {
#pragma unroll
    for (int ii = 0; ii < 2; ++ii) {
      const int i = i0 + ii;
      gld_lds16(&sA[slot][i * 4096 + (w << 9)],
                A + (size_t)(bm0 + i * 64 + (tid >> 3)) * K + kt * 64 + cswz);
    }
  };
  auto stageB = [&](int kt, int slot, int i0) {
#pragma unroll
    for (int ii = 0; ii < 2; ++ii) {
      const int i = i0 + ii;
      gld_lds16(&sB[slot][i * 4096 + (w << 9)],
                Bt + (size_t)(bn0 + i * 64 + (tid >> 3)) * K + kt * 64 + cswz);
    }
  };

  f32x4 acc[8][4];
#pragma unroll
  for (int mf = 0; mf < 8; mf++)
#pragma unroll
    for (int nf = 0; nf < 4; nf++)
#pragma unroll
      for (int r = 0; r < 4; r++) acc[mf][nf][r] = 0.0f;

  stageA(0, 0, 0); stageA(0, 0, 2);
  stageA(1, 1, 0); stageA(1, 1, 2);
  stageB(0, 0, 0); stageB(0, 0, 2);
  vmwait<0>();
  barrier_raw();

  int sa = 0, sa2 = 2;
#pragma unroll 1
  for (int t = 0; t < NT; ++t) {
    const int sb = t & 1, sb1 = sb ^ 1;
    half8 bfr[4][2];
#pragma unroll
    for (int nf = 0; nf < 4; nf++)
#pragma unroll
      for (int ks = 0; ks < 2; ks++) {
        const int brow = wn * 64 + nf * 16 + lo;
        bfr[nf][ks] = *(const half8*)&sB[sb][brow * 64 + (((ks * 4 + hi) ^ lo7) << 3)];
      }
    QPHASE(0, if (t + 1 < NT) stageB(t + 1, sb1, 0), )
    QPHASE(1, if (t + 1 < NT) stageB(t + 1, sb1, 2), )
    QPHASE(2, if (t + 2 < NT) stageA(t + 2, sa2, 0), )
    QPHASE(3, if (t + 2 < NT) stageA(t + 2, sa2, 2),
           if (t + 2 < NT) { vmwait<4>(); } else { vmwait<0>(); })
    sa = (sa == 2) ? 0 : sa + 1;
    sa2 = (sa2 == 2) ? 0 : sa2 + 1;
  }

  // C/D layout: col = lane&15, row = (lane>>4)*4 + reg  [m89/m91 verified]
#pragma unroll
  for (int mf = 0; mf < 8; mf++)
#pragma unroll
    for (int nf = 0; nf < 4; nf++)
#pragma unroll
      for (int r = 0; r < 4; r++)
        C[(size_t)(bm0 + wm * 128 + mf * 16 + hi * 4 + r) * N +
          (bn0 + wn * 64 + nf * 16 + lo)] = acc[mf][nf][r];
}

// ---------------- GEMM: proven R5 2-phase structure (used for out-projection) ------
template <int BM, bool F16OUT>
__global__ __launch_bounds__(256) void gemm_bt(const _Float16* __restrict__ A,
                                               const _Float16* __restrict__ Bt,
                                               void* __restrict__ Cv,
                                               int M, int N, int K) {
  constexpr int MF = BM / 32;   // per-wave m-frags
  constexpr int LA = BM / 64;   // per-wave A staging instrs per K-step
  __shared__ _Float16 sA[2][BM * 32];
  __shared__ _Float16 sB[2][128 * 32];
  const int tid = threadIdx.x;
  const int w = tid >> 6, l = tid & 63, lo = l & 15, hi = l >> 4;
  const int gx = gridDim.x, nwg = gx * gridDim.y;
  int bid = blockIdx.y * gx + blockIdx.x;
  bid = (bid & 7) * (nwg >> 3) + (bid >> 3);
  const int bn0 = (bid % gx) * 128, bm0 = (bid / gx) * BM;
  const int wm = w >> 1, wn = w & 1;
  const int srow = l >> 2;
  const int csel = ((l & 3) ^ ((l >> 3) & 3)) * 8;
  const int kswz = (hi ^ ((lo >> 1) & 3)) * 8;

  f32x4 acc[MF][4];
#pragma unroll
  for (int mi = 0; mi < MF; mi++)
#pragma unroll
    for (int ni = 0; ni < 4; ni++)
#pragma unroll
      for (int r = 0; r < 4; r++) acc[mi][ni][r] = 0.0f;

  auto stage = [&](int bi, int kt) {
#pragma unroll
    for (int i = 0; i < LA; ++i) {
      const int j = LA * w + i;
      gld_lds16(&sA[bi][j * 512],
                A + (size_t)(bm0 + j * 16 + srow) * K + (size_t)kt * 32 + csel);
    }
#pragma unroll
    for (int i = 0; i < 2; ++i) {
      const int j = 2 * w + i;
      gld_lds16(&sB[bi][j * 512],
                Bt + (size_t)(bn0 + j * 16 + srow) * K + (size_t)kt * 32 + csel);
    }
  };

  stage(0, 0);
  __syncthreads();
  const int KT = K >> 5;
#pragma unroll 1
  for (int kt = 0; kt < KT; ++kt) {
    const int cur = kt & 1;
    if (kt + 1 < KT) stage(cur ^ 1, kt + 1);
    half8 a[MF], b[4];
#pragma unroll
    for (int mi = 0; mi < MF; mi++)
      a[mi] = *(const half8*)&sA[cur][(wm * (BM / 2) + mi * 16 + lo) * 32 + kswz];
#pragma unroll
    for (int ni = 0; ni < 4; ni++)
      b[ni] = *(const half8*)&sB[cur][(wn * 64 + ni * 16 + lo) * 32 + kswz];
#pragma unroll
    for (int mi = 0; mi < MF; mi++)
#pragma unroll
      for (int ni = 0; ni < 4; ni++)
        acc[mi][ni] = __builtin_amdgcn_mfma_f32_16x16x32_f16(a[mi], b[ni], acc[mi][ni], 0, 0, 0);
    __syncthreads();
  }

#pragma unroll
  for (int mi = 0; mi < MF; mi++)
#pragma unroll
    for (int ni = 0; ni < 4; ni++)
#pragma unroll
      for (int r = 0; r < 4; r++) {
        const size_t idx = (size_t)(bm0 + wm * (BM / 2) + mi * 16 + hi * 4 + r) * N +
                           (bn0 + wn * 64 + ni * 16 + lo);
        if constexpr (F16OUT) ((_Float16*)Cv)[idx] = (_Float16)acc[mi][ni][r];
        else                  ((float*)Cv)[idx] = acc[mi][ni][r];
      }
}

// ---------------- fused RMSNorm+RoPE (Q,K) + V transpose, one launch --------------
__global__ __launch_bounds__(256) void post(const float* __restrict__ QKV,
                                            const int* __restrict__ pos,
                                            const float* __restrict__ qw,
                                            const float* __restrict__ kw,
                                            _Float16* __restrict__ Qb,
                                            _Float16* __restrict__ Kb,
                                            _Float16* __restrict__ Vt) {
  if (blockIdx.x >= 24576) {
    __shared__ float tt[32][33];
    const int g = blockIdx.x - 24576;
    const int tx = threadIdx.x & 31, ty = threadIdx.x >> 5;
    const int dt = g & 3;
    const int st = (g >> 2) & 63;
    const int bh = g >> 8;
    const float* src = QKV + (size_t)((bh >> 3) * 2048 + st * 32) * 4096 +
                       3072 + (bh & 7) * 128 + dt * 32;
#pragma unroll
    for (int i = 0; i < 4; i++)
      tt[ty + 8 * i][tx] = src[(size_t)(ty + 8 * i) * 4096 + tx];
    __syncthreads();
    _Float16* dst = Vt + ((size_t)bh * 128 + dt * 32) * 2048 + st * 32;
#pragma unroll
    for (int i = 0; i < 4; i++) {
      const int rr = ty + 8 * i;
      dst[(size_t)rr * 2048 + tx] = (_Float16)tt[tx][rr];
    }
    return;
  }
  const int w = threadIdx.x >> 6, l = threadIdx.x & 63;
  const int wv = blockIdx.x * 4 + w;
  const int t = wv / 24, hh = wv - t * 24;
  const int b = t >> 11, s = t & 2047;
  const bool isq = hh < 16;
  const int col = isq ? hh * 128 : 2048 + (hh - 16) * 128;
  const float* x = QKV + (size_t)t * 4096 + col;
  const float x1 = x[l], x2 = x[l + 64];
  float ss = x1 * x1 + x2 * x2;
  ss += __shfl_xor(ss, 32); ss += __shfl_xor(ss, 16); ss += __shfl_xor(ss, 8);
  ss += __shfl_xor(ss, 4);  ss += __shfl_xor(ss, 2);  ss += __shfl_xor(ss, 1);
  const float rn = rsqrtf(ss * 0.0078125f + 1e-6f);
  const float* wt = isq ? qw : kw;
  const float n1 = x1 * rn * wt[l], n2 = x2 * rn * wt[l + 64];
  const float ang = (float)pos[s] * exp2f((float)l * -0.2076205059304601f);
  float sa, ca;
  sincosf(ang, &sa, &ca);
  const float qs = isq ? 0.12751731f : 1.0f;  // SCALE * log2(e), Q only
  const float o1 = (n1 * ca - n2 * sa) * qs;
  const float o2 = (n2 * ca + n1 * sa) * qs;
  _Float16* dst = isq ? Qb + (((size_t)b * 16 + hh) * 2048 + s) * 128
                      : Kb + (((size_t)b * 8 + (hh - 16)) * 2048 + s) * 128;
  dst[l] = (_Float16)o1;
  dst[l + 64] = (_Float16)o2;
}

// ---------------- causal GQA flash attention ---------------------------------------
// R9-proven structure (LDS-staged K AND V, dbuf, swizzled, swapped QK^T, in-lane
// softmax). Single change vs R9: KVBLK 64 -> 32. LDS 74 -> 37 KB (sK 2x8 + sV 2x8 +
// P 5) => 4 blocks/CU (16 waves, 4/SIMD) vs 2. Four independent blocks per CU drift
// out of barrier-lockstep and overlap the serial QK^T->softmax->PV chain across the
// MFMA/VALU pipes. Mask applied on the last TWO 32-tiles (harmless where no masked
// elements exist).
__global__ __launch_bounds__(256, 4) void attn_fwd(const _Float16* __restrict__ Q,
                                                   const _Float16* __restrict__ K,
                                                   const _Float16* __restrict__ Vt,
                                                   _Float16* __restrict__ AO) {
  __shared__ _Float16 sK[2][32 * 128];   // 8 KB per buffer
  __shared__ _Float16 sV[2][128 * 32];   // 8 KB per buffer
  __shared__ _Float16 P[4][16 * 40];     // per-wave P tile (16 q x 32 kv, pad 40)
  const int tid = threadIdx.x, w = tid >> 6, l = tid & 63, lo = l & 15, hi = l >> 4;
  const int qt = 31 - (blockIdx.x >> 5);  // heavy-first launch order
  const int hq = blockIdx.x & 15;
  const int b = (blockIdx.x >> 4) & 1;
  const int hk = hq >> 1, q0 = qt * 64;
  const _Float16* Qh = Q + ((size_t)(b * 16 + hq) * 2048) * 128;
  const _Float16* Kh = K + ((size_t)(b * 8 + hk) * 2048) * 128;
  const _Float16* Vh = Vt + ((size_t)(b * 8 + hk) * 128) * 2048;
  const int qw0 = q0 + w * 16;

  // stage K tile [32][128] f16: 8 instrs x 1KB; instr covers 4 rows of 256B
  auto stageK = [&](int bi, int kv0) {
#pragma unroll
    for (int i = 0; i < 2; ++i) {
      const int inst = w * 2 + i;
      const int r = inst * 4 + (l >> 4);                 // kv row 0..31
      const int cb = ((l & 15) * 16) ^ ((r & 7) << 4);   // pre-swizzled source byte
      gld_lds16(&sK[bi][inst * 512],
                (const char*)Kh + (size_t)(kv0 + r) * 256 + cb);
    }
  };
  // stage V tile [128][32] f16: 8 instrs x 1KB; instr covers 16 rows of 64B
  auto stageV = [&](int bi, int kv0) {
#pragma unroll
    for (int i = 0; i < 2; ++i) {
      const int inst = w * 2 + i;
      const int r = inst * 16 + (l >> 2);                // d row 0..127
      const int cb = ((l & 3) * 16) ^ ((r & 3) << 4);    // 4-chunk XOR within 64B row
      gld_lds16(&sV[bi][inst * 512],
                (const char*)Vh + (size_t)r * 4096 + (size_t)kv0 * 2 + cb);
    }
  };

  half8 aq[4];
#pragma unroll
  for (int kc = 0; kc < 4; kc++)
    aq[kc] = *(const half8*)(Qh + (size_t)(qw0 + lo) * 128 + kc * 32 + hi * 8);

  f32x4 o[8];
#pragma unroll
  for (int dn = 0; dn < 8; dn++)
#pragma unroll
    for (int r = 0; r < 4; r++) o[dn][r] = 0.0f;
  float mrow = -1e30f, lrow = 0.0f;  // per-lane: q row = qw0 + lo

  const int nt = (qt + 1) * 2;  // 32-wide kv tiles
  stageK(0, 0);
  stageV(0, 0);
  __syncthreads();
#pragma unroll 1
  for (int kt = 0; kt < nt; ++kt) {
    const int kv0 = kt * 32;
    const int cur = kt & 1;
    if (kt + 1 < nt) {  // prefetch next tile; overlaps this tile's compute
      stageK(cur ^ 1, kv0 + 32);
      stageV(cur ^ 1, kv0 + 32);
    }
    const char* kb = (const char*)sK[cur];
    const char* vb = (const char*)sV[cur];
    // ---- S^T = K Q^T (swapped: M=kv32, N=q16, K=d128) ----
    // C layout: q = lane&15, kv = kv0 + ns*16 + hi*4 + r
    f32x4 s[2];
#pragma unroll
    for (int ns = 0; ns < 2; ns++) {
#pragma unroll
      for (int r = 0; r < 4; r++) s[ns][r] = 0.0f;
      const int krow = ns * 16 + lo;
#pragma unroll
      for (int kc = 0; kc < 4; kc++) {
        half8 bk = *(const half8*)(kb + krow * 256 +
                                   ((kc * 64 + hi * 16) ^ ((krow & 7) << 4)));
        s[ns] = __builtin_amdgcn_mfma_f32_16x16x32_f16(bk, aq[kc], s[ns], 0, 0, 0);
      }
    }
    // ---- causal mask: only the last two 32-tiles can contain masked entries ----
    if (kt >= nt - 2) {
#pragma unroll
      for (int ns = 0; ns < 2; ns++) {
        const int kv = kv0 + ns * 16 + hi * 4;
#pragma unroll
        for (int r = 0; r < 4; r++)
          if (kv + r > qw0 + lo) s[ns][r] = -1e30f;
      }
    }
    // ---- in-lane row max (8 vals) + cross-hi reduce (2 shuffles) ----
    float tmax = s[0][0];
#pragma unroll
    for (int ns = 0; ns < 2; ns++)
#pragma unroll
      for (int r = 0; r < 4; r++) tmax = fmaxf(tmax, s[ns][r]);
    tmax = fmaxf(tmax, __shfl_xor(tmax, 16));
    tmax = fmaxf(tmax, __shfl_xor(tmax, 32));
    // ---- defer-max (T13): skip rescale when max growth <= 8 (log2 units) ----
    if (!__all(tmax <= mrow + 8.0f)) {
      const float mn = fmaxf(mrow, tmax);
      const float corr = exp2f(mrow - mn);
      mrow = mn;
      lrow *= corr;
      float c4[4];
#pragma unroll
      for (int r = 0; r < 4; r++) c4[r] = __shfl(corr, hi * 4 + r, 16);
#pragma unroll
      for (int dn = 0; dn < 8; dn++)
#pragma unroll
        for (int r = 0; r < 4; r++) o[dn][r] *= c4[r];
    }
    // ---- P = exp2(S - m), packed ds_write_b64 ----
    float psum = 0.0f;
#pragma unroll
    for (int ns = 0; ns < 2; ns++) {
      half4 pk;
#pragma unroll
      for (int r = 0; r < 4; r++) {
        const float p = exp2f(s[ns][r] - mrow);
        psum += p;
        pk[r] = (_Float16)p;
      }
      *(half4*)&P[w][lo * 40 + ns * 16 + hi * 4] = pk;
    }
    psum += __shfl_xor(psum, 16);
    psum += __shfl_xor(psum, 32);
    lrow += psum;
    asm volatile("s_waitcnt lgkmcnt(0)" ::: "memory");
    half8 ap0 = *(const half8*)&P[w][lo * 40 + hi * 8];
    // ---- O += P V (M=q16, N=d128, K=kv32) ----
#pragma unroll
    for (int dn = 0; dn < 8; dn++) {
      const int vrow = dn * 16 + lo;
      half8 bv0 = *(const half8*)(vb + vrow * 64 + ((hi * 16) ^ ((vrow & 3) << 4)));
      o[dn] = __builtin_amdgcn_mfma_f32_16x16x32_f16(ap0, bv0, o[dn], 0, 0, 0);
    }
    __syncthreads();  // drains vmcnt(0): prefetch landed; sK/sV[cur] reads done
  }

  const float inv = 1.0f / lrow;
  float i4[4];
#pragma unroll
  for (int r = 0; r < 4; r++) i4[r] = __shfl(inv, hi * 4 + r, 16);
  const size_t tok = (size_t)b * 2048 + qw0;
#pragma unroll
  for (int dn = 0; dn < 8; dn++)
#pragma unroll
    for (int r = 0; r < 4; r++)
      AO[(tok + hi * 4 + r) * 2048 + hq * 128 + dn * 16 + lo] = (_Float16)(o[dn][r] * i4[r]);
}

// ---------------- launch ----------------
extern "C" void kernel_launch(void* const* d_in, const int* in_sizes, int n_in,
                              void* d_out, int out_size, void* d_ws, size_t ws_size,
                              hipStream_t stream) {
  (void)in_sizes; (void)n_in; (void)out_size; (void)ws_size;
  const float* hs  = (const float*)d_in[0];
  const int*   pos = (const int*)d_in[1];
  const float* Wq  = (const float*)d_in[2];
  const float* Wk  = (const float*)d_in[3];
  const float* Wv  = (const float*)d_in[4];
  const float* Wo  = (const float*)d_in[5];
  const float* qnw = (const float*)d_in[6];
  const float* knw = (const float*)d_in[7];
  float* out = (float*)d_out;

  char* ws = (char*)d_ws;
  size_t off = 0;
  auto take = [&](size_t bytes) -> void* {
    void* p = ws + off;
    off += (bytes + 255) & ~(size_t)255;
    return p;
  };
  _Float16* Xh    = (_Float16*)take((size_t)4096 * 2048 * 2);   // hidden f16
  _Float16* Wqkvt = (_Float16*)take((size_t)4096 * 2048 * 2);   // packed [Wq;Wk;Wv]^T
  _Float16* Wot   = (_Float16*)take((size_t)2048 * 2048 * 2);   // Wo^T
  float*    QKV   = (float*)take((size_t)4096 * 4096 * 4);      // projection out f32
  _Float16* Qb    = (_Float16*)take((size_t)2 * 16 * 2048 * 128 * 2);
  _Float16* Kb    = (_Float16*)take((size_t)2 * 8 * 2048 * 128 * 2);
  _Float16* Vt    = (_Float16*)take((size_t)2 * 8 * 128 * 2048 * 2);
  _Float16* AO    = (_Float16*)take((size_t)4096 * 2048 * 2);   // attention out f16

  prep<<<16384, 256, 0, stream>>>(hs, Wq, Wk, Wv, Wo, Xh, Wqkvt, Wot);
  gemm256<<<256, 512, 0, stream>>>(Xh, Wqkvt, QKV, 4096, 4096, 2048);
  post<<<28672, 256, 0, stream>>>(QKV, pos, qnw, knw, Qb, Kb, Vt);
  attn_fwd<<<1024, 256, 0, stream>>>(Qb, Kb, Vt, AO);
  gemm_bt<64, false><<<dim3(16, 64), 256, 0, stream>>>(AO, Wot, out, 4096, 2048, 2048);
}

// Round 13
// 240.017 us; speedup vs baseline: 1.2728x; 1.0358x over previous
//
#include <hip/hip_runtime.h>
#include <cstdint>
#include <cstddef>

// ---------------- types ----------------
typedef _Float16 half8 __attribute__((ext_vector_type(8)));
typedef _Float16 half4 __attribute__((ext_vector_type(4)));
typedef float f32x4 __attribute__((ext_vector_type(4)));

#define DI __device__ __forceinline__

// global -> LDS async copy, 16B per lane. LDS dest must be WAVE-UNIFORM; HW adds lane*16.
DI void gld_lds16(void* sp, const void* gp) {
  __builtin_amdgcn_global_load_lds(
      (const __attribute__((address_space(1))) void*)gp,
      (__attribute__((address_space(3))) void*)sp, 16, 0, 0);
}

template <int N>
DI void vmwait() { asm volatile("s_waitcnt vmcnt(%0)" :: "n"(N) : "memory"); }

// raw barrier (no vmcnt drain) with compiler-level memory fences on both sides
DI void barrier_raw() {
  asm volatile("" ::: "memory");
  __builtin_amdgcn_s_barrier();
  asm volatile("" ::: "memory");
}

// ---------------- merged weight/activation prep (1 launch) -----------------------
__global__ __launch_bounds__(256) void prep(const float* __restrict__ hs,
                                            const float* __restrict__ Wq,
                                            const float* __restrict__ Wk,
                                            const float* __restrict__ Wv,
                                            const float* __restrict__ Wo,
                                            _Float16* __restrict__ Xh,
                                            _Float16* __restrict__ Wqkvt,
                                            _Float16* __restrict__ Wot) {
  const int bid = blockIdx.x;
  if (bid >= 12288) {
    const int i = (bid - 12288) * 256 + threadIdx.x;
    const float4* p = (const float4*)hs + (size_t)i * 2;
    const float4 a = p[0], b = p[1];
    half8 h;
    h[0] = (_Float16)a.x; h[1] = (_Float16)a.y; h[2] = (_Float16)a.z; h[3] = (_Float16)a.w;
    h[4] = (_Float16)b.x; h[5] = (_Float16)b.y; h[6] = (_Float16)b.z; h[7] = (_Float16)b.w;
    *(half8*)(Xh + (size_t)i * 8) = h;
    return;
  }
  const float* in;
  _Float16* outp;
  int C, t;
  if (bid < 4096)      { in = Wq; outp = Wqkvt;                        C = 2048; t = bid; }
  else if (bid < 6144) { in = Wk; outp = Wqkvt + (size_t)2048 * 2048;  C = 1024; t = bid - 4096; }
  else if (bid < 8192) { in = Wv; outp = Wqkvt + (size_t)3072 * 2048;  C = 1024; t = bid - 6144; }
  else                 { in = Wo; outp = Wot;                          C = 2048; t = bid - 8192; }
  __shared__ float tl[32][33];
  const int tx = threadIdx.x & 31, ty = threadIdx.x >> 5;
  const int ctiles = C >> 5;
  const int tc = t % ctiles, tr = t / ctiles;
  const int r0 = tr * 32, c0 = tc * 32;
#pragma unroll
  for (int i = 0; i < 4; i++)
    tl[ty + 8 * i][tx] = in[(size_t)(r0 + ty + 8 * i) * C + c0 + tx];
  __syncthreads();
#pragma unroll
  for (int i = 0; i < 4; i++) {
    const int rr = ty + 8 * i;
    outp[(size_t)(c0 + rr) * 2048 + r0 + tx] = (_Float16)tl[tx][rr];
  }
}

// ---------------- 256xBN 8-phase GEMM (m201-template port, f16) --------------------
// Verified R9 at BN=256 (QKV, ~1.05 PF). BN is a parameter change on the verified
// template (two-lane discipline): BN=128 doubles the out-proj grid to 256 blocks
// (full CU coverage). Per K-tile t: 4 phases, each
//   { ds_read frags | stage half-tile -> s_barrier -> lgkmcnt(0)+sched_barrier(0)
//     -> setprio(1) MFMAs setprio(0) -> s_barrier }.
// ph1/ph2 stage B(t+1) halves; ph3/ph4 stage A(t+2) halves; ph4 vmwait<4> leaves
// ONLY A(t+2)'s 4 loads in flight (B-halves are 2 instrs at BN=256, 1 at BN=128;
// ledger closes either way). Never vmcnt(0) in steady state; raw barriers.
#define QPHASE(Q, STAGE, VMW)                                                  \
  {                                                                            \
    half8 afr[2][2];                                                           \
    _Pragma("unroll") for (int j = 0; j < 2; j++)                              \
      _Pragma("unroll") for (int ks = 0; ks < 2; ks++) {                       \
        const int arow = wm * 128 + ((Q) * 2 + j) * 16 + lo;                   \
        afr[j][ks] =                                                           \
            *(const half8*)&sA[sa][arow * 64 + (((ks * 4 + hi) ^ lo7) << 3)];  \
      }                                                                        \
    STAGE;                                                                     \
    VMW;                                                                       \
    barrier_raw();                                                             \
    asm volatile("s_waitcnt lgkmcnt(0)" ::: "memory");                         \
    __builtin_amdgcn_sched_barrier(0);                                         \
    __builtin_amdgcn_s_setprio(1);                                             \
    _Pragma("unroll") for (int j = 0; j < 2; j++)                              \
      _Pragma("unroll") for (int nf = 0; nf < NF; nf++)                        \
        _Pragma("unroll") for (int ks = 0; ks < 2; ks++)                       \
          acc[(Q) * 2 + j][nf] = __builtin_amdgcn_mfma_f32_16x16x32_f16(       \
              afr[j][ks], bfr[nf][ks], acc[(Q) * 2 + j][nf], 0, 0, 0);         \
    __builtin_amdgcn_s_setprio(0);                                             \
    barrier_raw();                                                             \
  }

template <int BN>
__global__ __launch_bounds__(512, 2) void gemm256(const _Float16* __restrict__ A,
                                                  const _Float16* __restrict__ Bt,
                                                  float* __restrict__ C,
                                                  int M, int N, int K) {
  constexpr int NF = BN / 64;    // per-wave n-frags (4 or 2)
  constexpr int LBH = BN / 128;  // staging instrs per B half-tile (2 or 1)
  constexpr int WN = BN / 4;     // per-wave n extent
  __shared__ _Float16 sA[3][16384];     // 3 x 32KB (256 rows x 64 k, swizzled)
  __shared__ _Float16 sB[2][BN * 64];   // 2 x (BN/256)*32KB
  const int tid = threadIdx.x, w = tid >> 6, l = tid & 63, lo = l & 15, hi = l >> 4;
  const int lo7 = lo & 7;
  const int wm = w >> 2, wn = w & 3;
  const int nbn = N / BN;
  const int nwg = gridDim.x;
  int bid = blockIdx.x;
  bid = (bid & 7) * (nwg >> 3) + (bid >> 3);  // bijective XCD remap (nwg % 8 == 0)
  const int bm0 = (bid / nbn) << 8, bn0 = (bid % nbn) * BN;
  const int cswz = ((tid & 7) ^ ((tid >> 3) & 7)) << 3;  // staged element col (inv-swz)
  const int NT = K >> 6;

  auto stageA = [&](int kt, int slot, int i0) {
#pragma unroll
    for (int ii = 0; ii < 2; ++ii) {
      const int i = i0 + ii;
      gld_lds16(&sA[slot][i * 4096 + (w << 9)],
                A + (size_t)(bm0 + i * 64 + (tid >> 3)) * K + kt * 64 + cswz);
    }
  };
  auto stageB = [&](int kt, int slot, int half) {
#pragma unroll
    for (int ii = 0; ii < LBH; ++ii) {
      const int i = half * LBH + ii;
      gld_lds16(&sB[slot][i * 4096 + (w << 9)],
                Bt + (size_t)(bn0 + i * 64 + (tid >> 3)) * K + kt * 64 + cswz);
    }
  };

  f32x4 acc[8][NF];
#pragma unroll
  for (int mf = 0; mf < 8; mf++)
#pragma unroll
    for (int nf = 0; nf < NF; nf++)
#pragma unroll
      for (int r = 0; r < 4; r++) acc[mf][nf][r] = 0.0f;

  stageA(0, 0, 0); stageA(0, 0, 2);
  stageA(1, 1, 0); stageA(1, 1, 2);
  stageB(0, 0, 0); stageB(0, 0, 1);
  vmwait<0>();
  barrier_raw();

  int sa = 0, sa2 = 2;
#pragma unroll 1
  for (int t = 0; t < NT; ++t) {
    const int sb = t & 1, sb1 = sb ^ 1;
    half8 bfr[NF][2];
#pragma unroll
    for (int nf = 0; nf < NF; nf++)
#pragma unroll
      for (int ks = 0; ks < 2; ks++) {
        const int brow = wn * WN + nf * 16 + lo;
        bfr[nf][ks] = *(const half8*)&sB[sb][brow * 64 + (((ks * 4 + hi) ^ lo7) << 3)];
      }
    QPHASE(0, if (t + 1 < NT) stageB(t + 1, sb1, 0), )
    QPHASE(1, if (t + 1 < NT) stageB(t + 1, sb1, 1), )
    QPHASE(2, if (t + 2 < NT) stageA(t + 2, sa2, 0), )
    QPHASE(3, if (t + 2 < NT) stageA(t + 2, sa2, 2),
           if (t + 2 < NT) { vmwait<4>(); } else { vmwait<0>(); })
    sa = (sa == 2) ? 0 : sa + 1;
    sa2 = (sa2 == 2) ? 0 : sa2 + 1;
  }

  // C/D layout: col = lane&15, row = (lane>>4)*4 + reg  [m89/m91 verified]
#pragma unroll
  for (int mf = 0; mf < 8; mf++)
#pragma unroll
    for (int nf = 0; nf < NF; nf++)
#pragma unroll
      for (int r = 0; r < 4; r++)
        C[(size_t)(bm0 + wm * 128 + mf * 16 + hi * 4 + r) * N +
          (bn0 + wn * WN + nf * 16 + lo)] = acc[mf][nf][r];
}

// ---------------- fused RMSNorm+RoPE (Q,K) + V transpose, one launch --------------
__global__ __launch_bounds__(256) void post(const float* __restrict__ QKV,
                                            const int* __restrict__ pos,
                                            const float* __restrict__ qw,
                                            const float* __restrict__ kw,
                                            _Float16* __restrict__ Qb,
                                            _Float16* __restrict__ Kb,
                                            _Float16* __restrict__ Vt) {
  if (blockIdx.x >= 24576) {
    __shared__ float tt[32][33];
    const int g = blockIdx.x - 24576;
    const int tx = threadIdx.x & 31, ty = threadIdx.x >> 5;
    const int dt = g & 3;
    const int st = (g >> 2) & 63;
    const int bh = g >> 8;
    const float* src = QKV + (size_t)((bh >> 3) * 2048 + st * 32) * 4096 +
                       3072 + (bh & 7) * 128 + dt * 32;
#pragma unroll
    for (int i = 0; i < 4; i++)
      tt[ty + 8 * i][tx] = src[(size_t)(ty + 8 * i) * 4096 + tx];
    __syncthreads();
    _Float16* dst = Vt + ((size_t)bh * 128 + dt * 32) * 2048 + st * 32;
#pragma unroll
    for (int i = 0; i < 4; i++) {
      const int rr = ty + 8 * i;
      dst[(size_t)rr * 2048 + tx] = (_Float16)tt[tx][rr];
    }
    return;
  }
  const int w = threadIdx.x >> 6, l = threadIdx.x & 63;
  const int wv = blockIdx.x * 4 + w;
  const int t = wv / 24, hh = wv - t * 24;
  const int b = t >> 11, s = t & 2047;
  const bool isq = hh < 16;
  const int col = isq ? hh * 128 : 2048 + (hh - 16) * 128;
  const float* x = QKV + (size_t)t * 4096 + col;
  const float x1 = x[l], x2 = x[l + 64];
  float ss = x1 * x1 + x2 * x2;
  ss += __shfl_xor(ss, 32); ss += __shfl_xor(ss, 16); ss += __shfl_xor(ss, 8);
  ss += __shfl_xor(ss, 4);  ss += __shfl_xor(ss, 2);  ss += __shfl_xor(ss, 1);
  const float rn = rsqrtf(ss * 0.0078125f + 1e-6f);
  const float* wt = isq ? qw : kw;
  const float n1 = x1 * rn * wt[l], n2 = x2 * rn * wt[l + 64];
  const float ang = (float)pos[s] * exp2f((float)l * -0.2076205059304601f);
  float sa, ca;
  sincosf(ang, &sa, &ca);
  const float qs = isq ? 0.12751731f : 1.0f;  // SCALE * log2(e), Q only
  const float o1 = (n1 * ca - n2 * sa) * qs;
  const float o2 = (n2 * ca + n1 * sa) * qs;
  _Float16* dst = isq ? Qb + (((size_t)b * 16 + hh) * 2048 + s) * 128
                      : Kb + (((size_t)b * 8 + (hh - 16)) * 2048 + s) * 128;
  dst[l] = (_Float16)o1;
  dst[l + 64] = (_Float16)o2;
}

// ---------------- causal GQA flash attention (R9-proven, KVBLK=64) -----------------
__global__ __launch_bounds__(256) void attn_fwd(const _Float16* __restrict__ Q,
                                                const _Float16* __restrict__ K,
                                                const _Float16* __restrict__ Vt,
                                                _Float16* __restrict__ AO) {
  __shared__ _Float16 sK[2][64 * 128];   // 16 KB per buffer
  __shared__ _Float16 sV[2][128 * 64];   // 16 KB per buffer
  __shared__ _Float16 P[4][16 * 80];     // per-wave P tile, padded stride 80
  const int tid = threadIdx.x, w = tid >> 6, l = tid & 63, lo = l & 15, hi = l >> 4;
  const int qt = 31 - (blockIdx.x >> 5);  // heavy-first launch order
  const int hq = blockIdx.x & 15;
  const int b = (blockIdx.x >> 4) & 1;
  const int hk = hq >> 1, q0 = qt * 64;
  const _Float16* Qh = Q + ((size_t)(b * 16 + hq) * 2048) * 128;
  const _Float16* Kh = K + ((size_t)(b * 8 + hk) * 2048) * 128;
  const _Float16* Vh = Vt + ((size_t)(b * 8 + hk) * 128) * 2048;
  const int qw0 = q0 + w * 16;

  auto stageK = [&](int bi, int kv0) {
#pragma unroll
    for (int i = 0; i < 4; ++i) {
      const int inst = w * 4 + i;
      const int r = inst * 4 + (l >> 4);
      const int cb = ((l & 15) * 16) ^ ((r & 7) << 4);
      gld_lds16(&sK[bi][inst * 512],
                (const char*)Kh + (size_t)(kv0 + r) * 256 + cb);
    }
  };
  auto stageV = [&](int bi, int kv0) {
#pragma unroll
    for (int i = 0; i < 4; ++i) {
      const int inst = w * 4 + i;
      const int r = inst * 8 + (l >> 3);
      const int cb = ((l & 7) * 16) ^ ((r & 7) << 4);
      gld_lds16(&sV[bi][inst * 512],
                (const char*)Vh + (size_t)r * 4096 + (size_t)kv0 * 2 + cb);
    }
  };

  half8 aq[4];
#pragma unroll
  for (int kc = 0; kc < 4; kc++)
    aq[kc] = *(const half8*)(Qh + (size_t)(qw0 + lo) * 128 + kc * 32 + hi * 8);

  f32x4 o[8];
#pragma unroll
  for (int dn = 0; dn < 8; dn++)
#pragma unroll
    for (int r = 0; r < 4; r++) o[dn][r] = 0.0f;
  float mrow = -1e30f, lrow = 0.0f;

  const int nt = qt + 1;
  stageK(0, 0);
  stageV(0, 0);
  __syncthreads();
#pragma unroll 1
  for (int kt = 0; kt < nt; ++kt) {
    const int kv0 = kt * 64;
    const int cur = kt & 1;
    if (kt + 1 < nt) {
      stageK(cur ^ 1, kv0 + 64);
      stageV(cur ^ 1, kv0 + 64);
    }
    const char* kb = (const char*)sK[cur];
    const char* vb = (const char*)sV[cur];
    f32x4 s[4];
#pragma unroll
    for (int ns = 0; ns < 4; ns++) {
#pragma unroll
      for (int r = 0; r < 4; r++) s[ns][r] = 0.0f;
      const int krow = ns * 16 + lo;
#pragma unroll
      for (int kc = 0; kc < 4; kc++) {
        half8 bk = *(const half8*)(kb + krow * 256 +
                                   ((kc * 64 + hi * 16) ^ ((krow & 7) << 4)));
        s[ns] = __builtin_amdgcn_mfma_f32_16x16x32_f16(bk, aq[kc], s[ns], 0, 0, 0);
      }
    }
    if (kt == nt - 1) {
#pragma unroll
      for (int ns = 0; ns < 4; ns++) {
        const int kv = kv0 + ns * 16 + hi * 4;
#pragma unroll
        for (int r = 0; r < 4; r++)
          if (kv + r > qw0 + lo) s[ns][r] = -1e30f;
      }
    }
    float tmax = s[0][0];
#pragma unroll
    for (int ns = 0; ns < 4; ns++)
#pragma unroll
      for (int r = 0; r < 4; r++) tmax = fmaxf(tmax, s[ns][r]);
    tmax = fmaxf(tmax, __shfl_xor(tmax, 16));
    tmax = fmaxf(tmax, __shfl_xor(tmax, 32));
    if (!__all(tmax <= mrow + 8.0f)) {
      const float mn = fmaxf(mrow, tmax);
      const float corr = exp2f(mrow - mn);
      mrow = mn;
      lrow *= corr;
      float c4[4];
#pragma unroll
      for (int r = 0; r < 4; r++) c4[r] = __shfl(corr, hi * 4 + r, 16);
#pragma unroll
      for (int dn = 0; dn < 8; dn++)
#pragma unroll
        for (int r = 0; r < 4; r++) o[dn][r] *= c4[r];
    }
    float psum = 0.0f;
#pragma unroll
    for (int ns = 0; ns < 4; ns++) {
      half4 pk;
#pragma unroll
      for (int r = 0; r < 4; r++) {
        const float p = exp2f(s[ns][r] - mrow);
        psum += p;
        pk[r] = (_Float16)p;
      }
      *(half4*)&P[w][lo * 80 + ns * 16 + hi * 4] = pk;
    }
    psum += __shfl_xor(psum, 16);
    psum += __shfl_xor(psum, 32);
    lrow += psum;
    asm volatile("s_waitcnt lgkmcnt(0)" ::: "memory");
    half8 ap0 = *(const half8*)&P[w][lo * 80 + hi * 8];
    half8 ap1 = *(const half8*)&P[w][lo * 80 + 32 + hi * 8];
#pragma unroll
    for (int dn = 0; dn < 8; dn++) {
      const int vrow = dn * 16 + lo;
      half8 bv0 = *(const half8*)(vb + vrow * 128 + ((hi * 16) ^ ((vrow & 7) << 4)));
      half8 bv1 = *(const half8*)(vb + vrow * 128 + ((64 + hi * 16) ^ ((vrow & 7) << 4)));
      o[dn] = __builtin_amdgcn_mfma_f32_16x16x32_f16(ap0, bv0, o[dn], 0, 0, 0);
      o[dn] = __builtin_amdgcn_mfma_f32_16x16x32_f16(ap1, bv1, o[dn], 0, 0, 0);
    }
    __syncthreads();
  }

  const float inv = 1.0f / lrow;
  float i4[4];
#pragma unroll
  for (int r = 0; r < 4; r++) i4[r] = __shfl(inv, hi * 4 + r, 16);
  const size_t tok = (size_t)b * 2048 + qw0;
#pragma unroll
  for (int dn = 0; dn < 8; dn++)
#pragma unroll
    for (int r = 0; r < 4; r++)
      AO[(tok + hi * 4 + r) * 2048 + hq * 128 + dn * 16 + lo] = (_Float16)(o[dn][r] * i4[r]);
}

// ---------------- launch ----------------
extern "C" void kernel_launch(void* const* d_in, const int* in_sizes, int n_in,
                              void* d_out, int out_size, void* d_ws, size_t ws_size,
                              hipStream_t stream) {
  (void)in_sizes; (void)n_in; (void)out_size; (void)ws_size;
  const float* hs  = (const float*)d_in[0];
  const int*   pos = (const int*)d_in[1];
  const float* Wq  = (const float*)d_in[2];
  const float* Wk  = (const float*)d_in[3];
  const float* Wv  = (const float*)d_in[4];
  const float* Wo  = (const float*)d_in[5];
  const float* qnw = (const float*)d_in[6];
  const float* knw = (const float*)d_in[7];
  float* out = (float*)d_out;

  char* ws = (char*)d_ws;
  size_t off = 0;
  auto take = [&](size_t bytes) -> void* {
    void* p = ws + off;
    off += (bytes + 255) & ~(size_t)255;
    return p;
  };
  _Float16* Xh    = (_Float16*)take((size_t)4096 * 2048 * 2);   // hidden f16
  _Float16* Wqkvt = (_Float16*)take((size_t)4096 * 2048 * 2);   // packed [Wq;Wk;Wv]^T
  _Float16* Wot   = (_Float16*)take((size_t)2048 * 2048 * 2);   // Wo^T
  float*    QKV   = (float*)take((size_t)4096 * 4096 * 4);      // projection out f32
  _Float16* Qb    = (_Float16*)take((size_t)2 * 16 * 2048 * 128 * 2);
  _Float16* Kb    = (_Float16*)take((size_t)2 * 8 * 2048 * 128 * 2);
  _Float16* Vt    = (_Float16*)take((size_t)2 * 8 * 128 * 2048 * 2);
  _Float16* AO    = (_Float16*)take((size_t)4096 * 2048 * 2);   // attention out f16

  prep<<<16384, 256, 0, stream>>>(hs, Wq, Wk, Wv, Wo, Xh, Wqkvt, Wot);
  gemm256<256><<<256, 512, 0, stream>>>(Xh, Wqkvt, QKV, 4096, 4096, 2048);
  post<<<28672, 256, 0, stream>>>(QKV, pos, qnw, knw, Qb, Kb, Vt);
  attn_fwd<<<1024, 256, 0, stream>>>(Qb, Kb, Vt, AO);
  gemm256<128><<<256, 512, 0, stream>>>(AO, Wot, out, 4096, 2048, 2048);
}

// Round 14
// 236.725 us; speedup vs baseline: 1.2905x; 1.0139x over previous
//
#include <hip/hip_runtime.h>
#include <cstdint>
#include <cstddef>

// ---------------- types ----------------
typedef _Float16 half8 __attribute__((ext_vector_type(8)));
typedef _Float16 half4 __attribute__((ext_vector_type(4)));
typedef float f32x4 __attribute__((ext_vector_type(4)));

#define DI __device__ __forceinline__

// global -> LDS async copy, 16B per lane. LDS dest must be WAVE-UNIFORM; HW adds lane*16.
DI void gld_lds16(void* sp, const void* gp) {
  __builtin_amdgcn_global_load_lds(
      (const __attribute__((address_space(1))) void*)gp,
      (__attribute__((address_space(3))) void*)sp, 16, 0, 0);
}

template <int N>
DI void vmwait() { asm volatile("s_waitcnt vmcnt(%0)" :: "n"(N) : "memory"); }

// raw barrier (no vmcnt drain) with compiler-level memory fences on both sides
DI void barrier_raw() {
  asm volatile("" ::: "memory");
  __builtin_amdgcn_s_barrier();
  asm volatile("" ::: "memory");
}

// ---------------- merged weight/activation prep (1 launch) -----------------------
__global__ __launch_bounds__(256) void prep(const float* __restrict__ hs,
                                            const float* __restrict__ Wq,
                                            const float* __restrict__ Wk,
                                            const float* __restrict__ Wv,
                                            const float* __restrict__ Wo,
                                            _Float16* __restrict__ Xh,
                                            _Float16* __restrict__ Wqkvt,
                                            _Float16* __restrict__ Wot) {
  const int bid = blockIdx.x;
  if (bid >= 12288) {
    const int i = (bid - 12288) * 256 + threadIdx.x;
    const float4* p = (const float4*)hs + (size_t)i * 2;
    const float4 a = p[0], b = p[1];
    half8 h;
    h[0] = (_Float16)a.x; h[1] = (_Float16)a.y; h[2] = (_Float16)a.z; h[3] = (_Float16)a.w;
    h[4] = (_Float16)b.x; h[5] = (_Float16)b.y; h[6] = (_Float16)b.z; h[7] = (_Float16)b.w;
    *(half8*)(Xh + (size_t)i * 8) = h;
    return;
  }
  const float* in;
  _Float16* outp;
  int C, t;
  if (bid < 4096)      { in = Wq; outp = Wqkvt;                        C = 2048; t = bid; }
  else if (bid < 6144) { in = Wk; outp = Wqkvt + (size_t)2048 * 2048;  C = 1024; t = bid - 4096; }
  else if (bid < 8192) { in = Wv; outp = Wqkvt + (size_t)3072 * 2048;  C = 1024; t = bid - 6144; }
  else                 { in = Wo; outp = Wot;                          C = 2048; t = bid - 8192; }
  __shared__ float tl[32][33];
  const int tx = threadIdx.x & 31, ty = threadIdx.x >> 5;
  const int ctiles = C >> 5;
  const int tc = t % ctiles, tr = t / ctiles;
  const int r0 = tr * 32, c0 = tc * 32;
#pragma unroll
  for (int i = 0; i < 4; i++)
    tl[ty + 8 * i][tx] = in[(size_t)(r0 + ty + 8 * i) * C + c0 + tx];
  __syncthreads();
#pragma unroll
  for (int i = 0; i < 4; i++) {
    const int rr = ty + 8 * i;
    outp[(size_t)(c0 + rr) * 2048 + r0 + tx] = (_Float16)tl[tx][rr];
  }
}

// ---------------- 256x256 8-phase GEMM (m201-template port, f16) -------------------
// Verified R9: QKV 2048-K at ~1.05+ PF. BN=128 variant tried R13: +4 us vs
// gemm_bt<64> (phase overhead dominates at NF=2) — out-proj stays on gemm_bt.
#define QPHASE(Q, STAGE, VMW)                                                  \
  {                                                                            \
    half8 afr[2][2];                                                           \
    _Pragma("unroll") for (int j = 0; j < 2; j++)                              \
      _Pragma("unroll") for (int ks = 0; ks < 2; ks++) {                       \
        const int arow = wm * 128 + ((Q) * 2 + j) * 16 + lo;                   \
        afr[j][ks] =                                                           \
            *(const half8*)&sA[sa][arow * 64 + (((ks * 4 + hi) ^ lo7) << 3)];  \
      }                                                                        \
    STAGE;                                                                     \
    VMW;                                                                       \
    barrier_raw();                                                             \
    asm volatile("s_waitcnt lgkmcnt(0)" ::: "memory");                         \
    __builtin_amdgcn_sched_barrier(0);                                         \
    __builtin_amdgcn_s_setprio(1);                                             \
    _Pragma("unroll") for (int j = 0; j < 2; j++)                              \
      _Pragma("unroll") for (int nf = 0; nf < 4; nf++)                         \
        _Pragma("unroll") for (int ks = 0; ks < 2; ks++)                       \
          acc[(Q) * 2 + j][nf] = __builtin_amdgcn_mfma_f32_16x16x32_f16(       \
              afr[j][ks], bfr[nf][ks], acc[(Q) * 2 + j][nf], 0, 0, 0);         \
    __builtin_amdgcn_s_setprio(0);                                             \
    barrier_raw();                                                             \
  }

__global__ __launch_bounds__(512, 2) void gemm256(const _Float16* __restrict__ A,
                                                  const _Float16* __restrict__ Bt,
                                                  float* __restrict__ C,
                                                  int M, int N, int K) {
  __shared__ _Float16 sA[3][16384];  // 3 x 32KB (256 rows x 64 k, swizzled)
  __shared__ _Float16 sB[2][16384];  // 2 x 32KB
  const int tid = threadIdx.x, w = tid >> 6, l = tid & 63, lo = l & 15, hi = l >> 4;
  const int lo7 = lo & 7;
  const int wm = w >> 2, wn = w & 3;
  const int nbn = N >> 8;
  const int nwg = gridDim.x;
  int bid = blockIdx.x;
  bid = (bid & 7) * (nwg >> 3) + (bid >> 3);  // bijective XCD remap (nwg % 8 == 0)
  const int bm0 = (bid / nbn) << 8, bn0 = (bid % nbn) << 8;
  const int cswz = ((tid & 7) ^ ((tid >> 3) & 7)) << 3;  // staged element col (inv-swz)
  const int NT = K >> 6;

  auto stageA = [&](int kt, int slot, int i0) {
#pragma unroll
    for (int ii = 0; ii < 2; ++ii) {
      const int i = i0 + ii;
      gld_lds16(&sA[slot][i * 4096 + (w << 9)],
                A + (size_t)(bm0 + i * 64 + (tid >> 3)) * K + kt * 64 + cswz);
    }
  };
  auto stageB = [&](int kt, int slot, int i0) {
#pragma unroll
    for (int ii = 0; ii < 2; ++ii) {
      const int i = i0 + ii;
      gld_lds16(&sB[slot][i * 4096 + (w << 9)],
                Bt + (size_t)(bn0 + i * 64 + (tid >> 3)) * K + kt * 64 + cswz);
    }
  };

  f32x4 acc[8][4];
#pragma unroll
  for (int mf = 0; mf < 8; mf++)
#pragma unroll
    for (int nf = 0; nf < 4; nf++)
#pragma unroll
      for (int r = 0; r < 4; r++) acc[mf][nf][r] = 0.0f;

  stageA(0, 0, 0); stageA(0, 0, 2);
  stageA(1, 1, 0); stageA(1, 1, 2);
  stageB(0, 0, 0); stageB(0, 0, 2);
  vmwait<0>();
  barrier_raw();

  int sa = 0, sa2 = 2;
#pragma unroll 1
  for (int t = 0; t < NT; ++t) {
    const int sb = t & 1, sb1 = sb ^ 1;
    half8 bfr[4][2];
#pragma unroll
    for (int nf = 0; nf < 4; nf++)
#pragma unroll
      for (int ks = 0; ks < 2; ks++) {
        const int brow = wn * 64 + nf * 16 + lo;
        bfr[nf][ks] = *(const half8*)&sB[sb][brow * 64 + (((ks * 4 + hi) ^ lo7) << 3)];
      }
    QPHASE(0, if (t + 1 < NT) stageB(t + 1, sb1, 0), )
    QPHASE(1, if (t + 1 < NT) stageB(t + 1, sb1, 2), )
    QPHASE(2, if (t + 2 < NT) stageA(t + 2, sa2, 0), )
    QPHASE(3, if (t + 2 < NT) stageA(t + 2, sa2, 2),
           if (t + 2 < NT) { vmwait<4>(); } else { vmwait<0>(); })
    sa = (sa == 2) ? 0 : sa + 1;
    sa2 = (sa2 == 2) ? 0 : sa2 + 1;
  }

  // C/D layout: col = lane&15, row = (lane>>4)*4 + reg  [m89/m91 verified]
#pragma unroll
  for (int mf = 0; mf < 8; mf++)
#pragma unroll
    for (int nf = 0; nf < 4; nf++)
#pragma unroll
      for (int r = 0; r < 4; r++)
        C[(size_t)(bm0 + wm * 128 + mf * 16 + hi * 4 + r) * N +
          (bn0 + wn * 64 + nf * 16 + lo)] = acc[mf][nf][r];
}

// ---------------- GEMM: proven R5 2-phase structure (out-projection) ---------------
template <int BM, bool F16OUT>
__global__ __launch_bounds__(256) void gemm_bt(const _Float16* __restrict__ A,
                                               const _Float16* __restrict__ Bt,
                                               void* __restrict__ Cv,
                                               int M, int N, int K) {
  constexpr int MF = BM / 32;   // per-wave m-frags
  constexpr int LA = BM / 64;   // per-wave A staging instrs per K-step
  __shared__ _Float16 sA[2][BM * 32];
  __shared__ _Float16 sB[2][128 * 32];
  const int tid = threadIdx.x;
  const int w = tid >> 6, l = tid & 63, lo = l & 15, hi = l >> 4;
  const int gx = gridDim.x, nwg = gx * gridDim.y;
  int bid = blockIdx.y * gx + blockIdx.x;
  bid = (bid & 7) * (nwg >> 3) + (bid >> 3);
  const int bn0 = (bid % gx) * 128, bm0 = (bid / gx) * BM;
  const int wm = w >> 1, wn = w & 1;
  const int srow = l >> 2;
  const int csel = ((l & 3) ^ ((l >> 3) & 3)) * 8;
  const int kswz = (hi ^ ((lo >> 1) & 3)) * 8;

  f32x4 acc[MF][4];
#pragma unroll
  for (int mi = 0; mi < MF; mi++)
#pragma unroll
    for (int ni = 0; ni < 4; ni++)
#pragma unroll
      for (int r = 0; r < 4; r++) acc[mi][ni][r] = 0.0f;

  auto stage = [&](int bi, int kt) {
#pragma unroll
    for (int i = 0; i < LA; ++i) {
      const int j = LA * w + i;
      gld_lds16(&sA[bi][j * 512],
                A + (size_t)(bm0 + j * 16 + srow) * K + (size_t)kt * 32 + csel);
    }
#pragma unroll
    for (int i = 0; i < 2; ++i) {
      const int j = 2 * w + i;
      gld_lds16(&sB[bi][j * 512],
                Bt + (size_t)(bn0 + j * 16 + srow) * K + (size_t)kt * 32 + csel);
    }
  };

  stage(0, 0);
  __syncthreads();
  const int KT = K >> 5;
#pragma unroll 1
  for (int kt = 0; kt < KT; ++kt) {
    const int cur = kt & 1;
    if (kt + 1 < KT) stage(cur ^ 1, kt + 1);
    half8 a[MF], b[4];
#pragma unroll
    for (int mi = 0; mi < MF; mi++)
      a[mi] = *(const half8*)&sA[cur][(wm * (BM / 2) + mi * 16 + lo) * 32 + kswz];
#pragma unroll
    for (int ni = 0; ni < 4; ni++)
      b[ni] = *(const half8*)&sB[cur][(wn * 64 + ni * 16 + lo) * 32 + kswz];
#pragma unroll
    for (int mi = 0; mi < MF; mi++)
#pragma unroll
      for (int ni = 0; ni < 4; ni++)
        acc[mi][ni] = __builtin_amdgcn_mfma_f32_16x16x32_f16(a[mi], b[ni], acc[mi][ni], 0, 0, 0);
    __syncthreads();
  }

#pragma unroll
  for (int mi = 0; mi < MF; mi++)
#pragma unroll
    for (int ni = 0; ni < 4; ni++)
#pragma unroll
      for (int r = 0; r < 4; r++) {
        const size_t idx = (size_t)(bm0 + wm * (BM / 2) + mi * 16 + hi * 4 + r) * N +
                           (bn0 + wn * 64 + ni * 16 + lo);
        if constexpr (F16OUT) ((_Float16*)Cv)[idx] = (_Float16)acc[mi][ni][r];
        else                  ((float*)Cv)[idx] = acc[mi][ni][r];
      }
}

// ---------------- fused RMSNorm+RoPE (Q,K) + V transpose, one launch --------------
__global__ __launch_bounds__(256) void post(const float* __restrict__ QKV,
                                            const int* __restrict__ pos,
                                            const float* __restrict__ qw,
                                            const float* __restrict__ kw,
                                            _Float16* __restrict__ Qb,
                                            _Float16* __restrict__ Kb,
                                            _Float16* __restrict__ Vt) {
  if (blockIdx.x >= 24576) {
    __shared__ float tt[32][33];
    const int g = blockIdx.x - 24576;
    const int tx = threadIdx.x & 31, ty = threadIdx.x >> 5;
    const int dt = g & 3;
    const int st = (g >> 2) & 63;
    const int bh = g >> 8;
    const float* src = QKV + (size_t)((bh >> 3) * 2048 + st * 32) * 4096 +
                       3072 + (bh & 7) * 128 + dt * 32;
#pragma unroll
    for (int i = 0; i < 4; i++)
      tt[ty + 8 * i][tx] = src[(size_t)(ty + 8 * i) * 4096 + tx];
    __syncthreads();
    _Float16* dst = Vt + ((size_t)bh * 128 + dt * 32) * 2048 + st * 32;
#pragma unroll
    for (int i = 0; i < 4; i++) {
      const int rr = ty + 8 * i;
      dst[(size_t)rr * 2048 + tx] = (_Float16)tt[tx][rr];
    }
    return;
  }
  const int w = threadIdx.x >> 6, l = threadIdx.x & 63;
  const int wv = blockIdx.x * 4 + w;
  const int t = wv / 24, hh = wv - t * 24;
  const int b = t >> 11, s = t & 2047;
  const bool isq = hh < 16;
  const int col = isq ? hh * 128 : 2048 + (hh - 16) * 128;
  const float* x = QKV + (size_t)t * 4096 + col;
  const float x1 = x[l], x2 = x[l + 64];
  float ss = x1 * x1 + x2 * x2;
  ss += __shfl_xor(ss, 32); ss += __shfl_xor(ss, 16); ss += __shfl_xor(ss, 8);
  ss += __shfl_xor(ss, 4);  ss += __shfl_xor(ss, 2);  ss += __shfl_xor(ss, 1);
  const float rn = rsqrtf(ss * 0.0078125f + 1e-6f);
  const float* wt = isq ? qw : kw;
  const float n1 = x1 * rn * wt[l], n2 = x2 * rn * wt[l + 64];
  const float ang = (float)pos[s] * exp2f((float)l * -0.2076205059304601f);
  float sa, ca;
  sincosf(ang, &sa, &ca);
  const float qs = isq ? 0.12751731f : 1.0f;  // SCALE * log2(e), Q only
  const float o1 = (n1 * ca - n2 * sa) * qs;
  const float o2 = (n2 * ca + n1 * sa) * qs;
  _Float16* dst = isq ? Qb + (((size_t)b * 16 + hh) * 2048 + s) * 128
                      : Kb + (((size_t)b * 8 + (hh - 16)) * 2048 + s) * 128;
  dst[l] = (_Float16)o1;
  dst[l + 64] = (_Float16)o2;
}

// ---------------- causal GQA flash attention (R9 structure, P stride 80->72) -------
// P stride 72 halfs (144 B = 4 banks mod 32): b128 reads land 8 lanes per 4-bank
// group (= the 8-cycle b128 floor, conflict-free); b64 writes 2-way (free, m136).
// Old stride 80 (160 B = 8 banks mod 32) was 4-way on both paths = ~7.5M conflict
// cycles (R9/R13 counter, matches 96 cyc x 67.6K wave-tiles arithmetic).
__global__ __launch_bounds__(256) void attn_fwd(const _Float16* __restrict__ Q,
                                                const _Float16* __restrict__ K,
                                                const _Float16* __restrict__ Vt,
                                                _Float16* __restrict__ AO) {
  __shared__ _Float16 sK[2][64 * 128];   // 16 KB per buffer
  __shared__ _Float16 sV[2][128 * 64];   // 16 KB per buffer
  __shared__ _Float16 P[4][16 * 72];     // per-wave P tile, stride 72
  const int tid = threadIdx.x, w = tid >> 6, l = tid & 63, lo = l & 15, hi = l >> 4;
  const int qt = 31 - (blockIdx.x >> 5);  // heavy-first launch order
  const int hq = blockIdx.x & 15;
  const int b = (blockIdx.x >> 4) & 1;
  const int hk = hq >> 1, q0 = qt * 64;
  const _Float16* Qh = Q + ((size_t)(b * 16 + hq) * 2048) * 128;
  const _Float16* Kh = K + ((size_t)(b * 8 + hk) * 2048) * 128;
  const _Float16* Vh = Vt + ((size_t)(b * 8 + hk) * 128) * 2048;
  const int qw0 = q0 + w * 16;

  auto stageK = [&](int bi, int kv0) {
#pragma unroll
    for (int i = 0; i < 4; ++i) {
      const int inst = w * 4 + i;
      const int r = inst * 4 + (l >> 4);
      const int cb = ((l & 15) * 16) ^ ((r & 7) << 4);
      gld_lds16(&sK[bi][inst * 512],
                (const char*)Kh + (size_t)(kv0 + r) * 256 + cb);
    }
  };
  auto stageV = [&](int bi, int kv0) {
#pragma unroll
    for (int i = 0; i < 4; ++i) {
      const int inst = w * 4 + i;
      const int r = inst * 8 + (l >> 3);
      const int cb = ((l & 7) * 16) ^ ((r & 7) << 4);
      gld_lds16(&sV[bi][inst * 512],
                (const char*)Vh + (size_t)r * 4096 + (size_t)kv0 * 2 + cb);
    }
  };

  half8 aq[4];
#pragma unroll
  for (int kc = 0; kc < 4; kc++)
    aq[kc] = *(const half8*)(Qh + (size_t)(qw0 + lo) * 128 + kc * 32 + hi * 8);

  f32x4 o[8];
#pragma unroll
  for (int dn = 0; dn < 8; dn++)
#pragma unroll
    for (int r = 0; r < 4; r++) o[dn][r] = 0.0f;
  float mrow = -1e30f, lrow = 0.0f;

  const int nt = qt + 1;
  stageK(0, 0);
  stageV(0, 0);
  __syncthreads();
#pragma unroll 1
  for (int kt = 0; kt < nt; ++kt) {
    const int kv0 = kt * 64;
    const int cur = kt & 1;
    if (kt + 1 < nt) {
      stageK(cur ^ 1, kv0 + 64);
      stageV(cur ^ 1, kv0 + 64);
    }
    const char* kb = (const char*)sK[cur];
    const char* vb = (const char*)sV[cur];
    f32x4 s[4];
#pragma unroll
    for (int ns = 0; ns < 4; ns++) {
#pragma unroll
      for (int r = 0; r < 4; r++) s[ns][r] = 0.0f;
      const int krow = ns * 16 + lo;
#pragma unroll
      for (int kc = 0; kc < 4; kc++) {
        half8 bk = *(const half8*)(kb + krow * 256 +
                                   ((kc * 64 + hi * 16) ^ ((krow & 7) << 4)));
        s[ns] = __builtin_amdgcn_mfma_f32_16x16x32_f16(bk, aq[kc], s[ns], 0, 0, 0);
      }
    }
    if (kt == nt - 1) {
#pragma unroll
      for (int ns = 0; ns < 4; ns++) {
        const int kv = kv0 + ns * 16 + hi * 4;
#pragma unroll
        for (int r = 0; r < 4; r++)
          if (kv + r > qw0 + lo) s[ns][r] = -1e30f;
      }
    }
    float tmax = s[0][0];
#pragma unroll
    for (int ns = 0; ns < 4; ns++)
#pragma unroll
      for (int r = 0; r < 4; r++) tmax = fmaxf(tmax, s[ns][r]);
    tmax = fmaxf(tmax, __shfl_xor(tmax, 16));
    tmax = fmaxf(tmax, __shfl_xor(tmax, 32));
    if (!__all(tmax <= mrow + 8.0f)) {
      const float mn = fmaxf(mrow, tmax);
      const float corr = exp2f(mrow - mn);
      mrow = mn;
      lrow *= corr;
      float c4[4];
#pragma unroll
      for (int r = 0; r < 4; r++) c4[r] = __shfl(corr, hi * 4 + r, 16);
#pragma unroll
      for (int dn = 0; dn < 8; dn++)
#pragma unroll
        for (int r = 0; r < 4; r++) o[dn][r] *= c4[r];
    }
    float psum = 0.0f;
#pragma unroll
    for (int ns = 0; ns < 4; ns++) {
      half4 pk;
#pragma unroll
      for (int r = 0; r < 4; r++) {
        const float p = exp2f(s[ns][r] - mrow);
        psum += p;
        pk[r] = (_Float16)p;
      }
      *(half4*)&P[w][lo * 72 + ns * 16 + hi * 4] = pk;
    }
    psum += __shfl_xor(psum, 16);
    psum += __shfl_xor(psum, 32);
    lrow += psum;
    asm volatile("s_waitcnt lgkmcnt(0)" ::: "memory");
    half8 ap0 = *(const half8*)&P[w][lo * 72 + hi * 8];
    half8 ap1 = *(const half8*)&P[w][lo * 72 + 32 + hi * 8];
#pragma unroll
    for (int dn = 0; dn < 8; dn++) {
      const int vrow = dn * 16 + lo;
      half8 bv0 = *(const half8*)(vb + vrow * 128 + ((hi * 16) ^ ((vrow & 7) << 4)));
      half8 bv1 = *(const half8*)(vb + vrow * 128 + ((64 + hi * 16) ^ ((vrow & 7) << 4)));
      o[dn] = __builtin_amdgcn_mfma_f32_16x16x32_f16(ap0, bv0, o[dn], 0, 0, 0);
      o[dn] = __builtin_amdgcn_mfma_f32_16x16x32_f16(ap1, bv1, o[dn], 0, 0, 0);
    }
    __syncthreads();
  }

  const float inv = 1.0f / lrow;
  float i4[4];
#pragma unroll
  for (int r = 0; r < 4; r++) i4[r] = __shfl(inv, hi * 4 + r, 16);
  const size_t tok = (size_t)b * 2048 + qw0;
#pragma unroll
  for (int dn = 0; dn < 8; dn++)
#pragma unroll
    for (int r = 0; r < 4; r++)
      AO[(tok + hi * 4 + r) * 2048 + hq * 128 + dn * 16 + lo] = (_Float16)(o[dn][r] * i4[r]);
}

// ---------------- launch ----------------
extern "C" void kernel_launch(void* const* d_in, const int* in_sizes, int n_in,
                              void* d_out, int out_size, void* d_ws, size_t ws_size,
                              hipStream_t stream) {
  (void)in_sizes; (void)n_in; (void)out_size; (void)ws_size;
  const float* hs  = (const float*)d_in[0];
  const int*   pos = (const int*)d_in[1];
  const float* Wq  = (const float*)d_in[2];
  const float* Wk  = (const float*)d_in[3];
  const float* Wv  = (const float*)d_in[4];
  const float* Wo  = (const float*)d_in[5];
  const float* qnw = (const float*)d_in[6];
  const float* knw = (const float*)d_in[7];
  float* out = (float*)d_out;

  char* ws = (char*)d_ws;
  size_t off = 0;
  auto take = [&](size_t bytes) -> void* {
    void* p = ws + off;
    off += (bytes + 255) & ~(size_t)255;
    return p;
  };
  _Float16* Xh    = (_Float16*)take((size_t)4096 * 2048 * 2);   // hidden f16
  _Float16* Wqkvt = (_Float16*)take((size_t)4096 * 2048 * 2);   // packed [Wq;Wk;Wv]^T
  _Float16* Wot   = (_Float16*)take((size_t)2048 * 2048 * 2);   // Wo^T
  float*    QKV   = (float*)take((size_t)4096 * 4096 * 4);      // projection out f32
  _Float16* Qb    = (_Float16*)take((size_t)2 * 16 * 2048 * 128 * 2);
  _Float16* Kb    = (_Float16*)take((size_t)2 * 8 * 2048 * 128 * 2);
  _Float16* Vt    = (_Float16*)take((size_t)2 * 8 * 128 * 2048 * 2);
  _Float16* AO    = (_Float16*)take((size_t)4096 * 2048 * 2);   // attention out f16

  prep<<<16384, 256, 0, stream>>>(hs, Wq, Wk, Wv, Wo, Xh, Wqkvt, Wot);
  gemm256<<<256, 512, 0, stream>>>(Xh, Wqkvt, QKV, 4096, 4096, 2048);
  post<<<28672, 256, 0, stream>>>(QKV, pos, qnw, knw, Qb, Kb, Vt);
  attn_fwd<<<1024, 256, 0, stream>>>(Qb, Kb, Vt, AO);
  gemm_bt<64, false><<<dim3(16, 64), 256, 0, stream>>>(AO, Wot, out, 4096, 2048, 2048);
}

// Round 15
// 232.900 us; speedup vs baseline: 1.3117x; 1.0164x over previous
//
#include <hip/hip_runtime.h>
#include <cstdint>
#include <cstddef>

// ---------------- types ----------------
typedef _Float16 half8 __attribute__((ext_vector_type(8)));
typedef _Float16 half4 __attribute__((ext_vector_type(4)));
typedef float f32x4 __attribute__((ext_vector_type(4)));

#define DI __device__ __forceinline__

// global -> LDS async copy, 16B per lane. LDS dest must be WAVE-UNIFORM; HW adds lane*16.
DI void gld_lds16(void* sp, const void* gp) {
  __builtin_amdgcn_global_load_lds(
      (const __attribute__((address_space(1))) void*)gp,
      (__attribute__((address_space(3))) void*)sp, 16, 0, 0);
}

template <int N>
DI void vmwait() { asm volatile("s_waitcnt vmcnt(%0)" :: "n"(N) : "memory"); }

// raw barrier (no vmcnt drain) with compiler-level memory fences on both sides
DI void barrier_raw() {
  asm volatile("" ::: "memory");
  __builtin_amdgcn_s_barrier();
  asm volatile("" ::: "memory");
}

DI unsigned pk16(float a, float b) {
  _Float16 ha = (_Float16)a, hb = (_Float16)b;
  unsigned short ua = __builtin_bit_cast(unsigned short, ha);
  unsigned short ub = __builtin_bit_cast(unsigned short, hb);
  return (unsigned)ua | ((unsigned)ub << 16);
}

// ---------------- merged weight/activation prep (1 launch) -----------------------
__global__ __launch_bounds__(256) void prep(const float* __restrict__ hs,
                                            const float* __restrict__ Wq,
                                            const float* __restrict__ Wk,
                                            const float* __restrict__ Wv,
                                            const float* __restrict__ Wo,
                                            _Float16* __restrict__ Xh,
                                            _Float16* __restrict__ Wqkvt,
                                            _Float16* __restrict__ Wot) {
  const int bid = blockIdx.x;
  if (bid >= 12288) {
    const int i = (bid - 12288) * 256 + threadIdx.x;
    const float4* p = (const float4*)hs + (size_t)i * 2;
    const float4 a = p[0], b = p[1];
    half8 h;
    h[0] = (_Float16)a.x; h[1] = (_Float16)a.y; h[2] = (_Float16)a.z; h[3] = (_Float16)a.w;
    h[4] = (_Float16)b.x; h[5] = (_Float16)b.y; h[6] = (_Float16)b.z; h[7] = (_Float16)b.w;
    *(half8*)(Xh + (size_t)i * 8) = h;
    return;
  }
  const float* in;
  _Float16* outp;
  int C, t;
  if (bid < 4096)      { in = Wq; outp = Wqkvt;                        C = 2048; t = bid; }
  else if (bid < 6144) { in = Wk; outp = Wqkvt + (size_t)2048 * 2048;  C = 1024; t = bid - 4096; }
  else if (bid < 8192) { in = Wv; outp = Wqkvt + (size_t)3072 * 2048;  C = 1024; t = bid - 6144; }
  else                 { in = Wo; outp = Wot;                          C = 2048; t = bid - 8192; }
  __shared__ float tl[32][33];
  const int tx = threadIdx.x & 31, ty = threadIdx.x >> 5;
  const int ctiles = C >> 5;
  const int tc = t % ctiles, tr = t / ctiles;
  const int r0 = tr * 32, c0 = tc * 32;
#pragma unroll
  for (int i = 0; i < 4; i++)
    tl[ty + 8 * i][tx] = in[(size_t)(r0 + ty + 8 * i) * C + c0 + tx];
  __syncthreads();
#pragma unroll
  for (int i = 0; i < 4; i++) {
    const int rr = ty + 8 * i;
    outp[(size_t)(c0 + rr) * 2048 + r0 + tx] = (_Float16)tl[tx][rr];
  }
}

// ---------------- 256x256 8-phase GEMM (m201-template port, f16) -------------------
// Verified R9 at ~1 PF (QKV). This round: f16 C-stores via in-wave shuffle repack —
// each lane stores half4 of 4 CONSECUTIVE cols (16 lanes x 8B = 128B full lines, no
// L2 RMW; R6's naive f16 stores were 32B partials = +61MB FETCH). Permutation:
// lane(hi,lo) target cols 4lo..4lo+3 (all nf=lo>>2) from src lanes hi*16+4*(lo&3)+j.
#define QPHASE(Q, STAGE, VMW)                                                  \
  {                                                                            \
    half8 afr[2][2];                                                           \
    _Pragma("unroll") for (int j = 0; j < 2; j++)                              \
      _Pragma("unroll") for (int ks = 0; ks < 2; ks++) {                       \
        const int arow = wm * 128 + ((Q) * 2 + j) * 16 + lo;                   \
        afr[j][ks] =                                                           \
            *(const half8*)&sA[sa][arow * 64 + (((ks * 4 + hi) ^ lo7) << 3)];  \
      }                                                                        \
    STAGE;                                                                     \
    VMW;                                                                       \
    barrier_raw();                                                             \
    asm volatile("s_waitcnt lgkmcnt(0)" ::: "memory");                         \
    __builtin_amdgcn_sched_barrier(0);                                         \
    __builtin_amdgcn_s_setprio(1);                                             \
    _Pragma("unroll") for (int j = 0; j < 2; j++)                              \
      _Pragma("unroll") for (int nf = 0; nf < 4; nf++)                         \
        _Pragma("unroll") for (int ks = 0; ks < 2; ks++)                       \
          acc[(Q) * 2 + j][nf] = __builtin_amdgcn_mfma_f32_16x16x32_f16(       \
              afr[j][ks], bfr[nf][ks], acc[(Q) * 2 + j][nf], 0, 0, 0);         \
    __builtin_amdgcn_s_setprio(0);                                             \
    barrier_raw();                                                             \
  }

__global__ __launch_bounds__(512, 2) void gemm256(const _Float16* __restrict__ A,
                                                  const _Float16* __restrict__ Bt,
                                                  _Float16* __restrict__ C,
                                                  int M, int N, int K) {
  __shared__ _Float16 sA[3][16384];  // 3 x 32KB (256 rows x 64 k, swizzled)
  __shared__ _Float16 sB[2][16384];  // 2 x 32KB
  const int tid = threadIdx.x, w = tid >> 6, l = tid & 63, lo = l & 15, hi = l >> 4;
  const int lo7 = lo & 7;
  const int wm = w >> 2, wn = w & 3;
  const int nbn = N >> 8;
  const int nwg = gridDim.x;
  int bid = blockIdx.x;
  bid = (bid & 7) * (nwg >> 3) + (bid >> 3);  // bijective XCD remap (nwg % 8 == 0)
  const int bm0 = (bid / nbn) << 8, bn0 = (bid % nbn) << 8;
  const int cswz = ((tid & 7) ^ ((tid >> 3) & 7)) << 3;  // staged element col (inv-swz)
  const int NT = K >> 6;

  auto stageA = [&](int kt, int slot, int i0) {
#pragma unroll
    for (int ii = 0; ii < 2; ++ii) {
      const int i = i0 + ii;
      gld_lds16(&sA[slot][i * 4096 + (w << 9)],
                A + (size_t)(bm0 + i * 64 + (tid >> 3)) * K + kt * 64 + cswz);
    }
  };
  auto stageB = [&](int kt, int slot, int i0) {
#pragma unroll
    for (int ii = 0; ii < 2; ++ii) {
      const int i = i0 + ii;
      gld_lds16(&sB[slot][i * 4096 + (w << 9)],
                Bt + (size_t)(bn0 + i * 64 + (tid >> 3)) * K + kt * 64 + cswz);
    }
  };

  f32x4 acc[8][4];
#pragma unroll
  for (int mf = 0; mf < 8; mf++)
#pragma unroll
    for (int nf = 0; nf < 4; nf++)
#pragma unroll
      for (int r = 0; r < 4; r++) acc[mf][nf][r] = 0.0f;

  stageA(0, 0, 0); stageA(0, 0, 2);
  stageA(1, 1, 0); stageA(1, 1, 2);
  stageB(0, 0, 0); stageB(0, 0, 2);
  vmwait<0>();
  barrier_raw();

  int sa = 0, sa2 = 2;
#pragma unroll 1
  for (int t = 0; t < NT; ++t) {
    const int sb = t & 1, sb1 = sb ^ 1;
    half8 bfr[4][2];
#pragma unroll
    for (int nf = 0; nf < 4; nf++)
#pragma unroll
      for (int ks = 0; ks < 2; ks++) {
        const int brow = wn * 64 + nf * 16 + lo;
        bfr[nf][ks] = *(const half8*)&sB[sb][brow * 64 + (((ks * 4 + hi) ^ lo7) << 3)];
      }
    QPHASE(0, if (t + 1 < NT) stageB(t + 1, sb1, 0), )
    QPHASE(1, if (t + 1 < NT) stageB(t + 1, sb1, 2), )
    QPHASE(2, if (t + 2 < NT) stageA(t + 2, sa2, 0), )
    QPHASE(3, if (t + 2 < NT) stageA(t + 2, sa2, 2),
           if (t + 2 < NT) { vmwait<4>(); } else { vmwait<0>(); })
    sa = (sa == 2) ? 0 : sa + 1;
    sa2 = (sa2 == 2) ? 0 : sa2 + 1;
  }

  // ---- f16 epilogue: shuffle-repack to full-line half4 stores ----
  // C/D layout: col = lane&15, row = (lane>>4)*4 + reg [m89/m91]. Lane (hi,lo)
  // stores cols 4lo..4lo+3 of row (mf,hi,r); all 4 share nf = lo>>2 and come from
  // src lanes hi*16 + 4*(lo&3) + j.
  const int nfsel = lo >> 2;
  const int sbase = hi * 16 + 4 * (lo & 3);
#pragma unroll
  for (int mf = 0; mf < 8; mf++)
#pragma unroll
    for (int r = 0; r < 4; r++) {
      const unsigned p01 = pk16(acc[mf][0][r], acc[mf][1][r]);  // cols c, c+16
      const unsigned p23 = pk16(acc[mf][2][r], acc[mf][3][r]);  // cols c+32, c+48
      unsigned h[4];
#pragma unroll
      for (int j = 0; j < 4; j++) {
        const unsigned w01 = (unsigned)__shfl((int)p01, sbase + j, 64);
        const unsigned w23 = (unsigned)__shfl((int)p23, sbase + j, 64);
        const unsigned wp = (nfsel & 2) ? w23 : w01;
        h[j] = (nfsel & 1) ? (wp >> 16) : (wp & 0xffffu);
      }
      const uint2 ov = make_uint2(h[0] | (h[1] << 16), h[2] | (h[3] << 16));
      *(uint2*)&C[(size_t)(bm0 + wm * 128 + mf * 16 + hi * 4 + r) * N +
                  (bn0 + wn * 64 + 4 * lo)] = ov;
    }
}

// ---------------- GEMM: proven R5 2-phase structure (out-projection) ---------------
template <int BM, bool F16OUT>
__global__ __launch_bounds__(256) void gemm_bt(const _Float16* __restrict__ A,
                                               const _Float16* __restrict__ Bt,
                                               void* __restrict__ Cv,
                                               int M, int N, int K) {
  constexpr int MF = BM / 32;   // per-wave m-frags
  constexpr int LA = BM / 64;   // per-wave A staging instrs per K-step
  __shared__ _Float16 sA[2][BM * 32];
  __shared__ _Float16 sB[2][128 * 32];
  const int tid = threadIdx.x;
  const int w = tid >> 6, l = tid & 63, lo = l & 15, hi = l >> 4;
  const int gx = gridDim.x, nwg = gx * gridDim.y;
  int bid = blockIdx.y * gx + blockIdx.x;
  bid = (bid & 7) * (nwg >> 3) + (bid >> 3);
  const int bn0 = (bid % gx) * 128, bm0 = (bid / gx) * BM;
  const int wm = w >> 1, wn = w & 1;
  const int srow = l >> 2;
  const int csel = ((l & 3) ^ ((l >> 3) & 3)) * 8;
  const int kswz = (hi ^ ((lo >> 1) & 3)) * 8;

  f32x4 acc[MF][4];
#pragma unroll
  for (int mi = 0; mi < MF; mi++)
#pragma unroll
    for (int ni = 0; ni < 4; ni++)
#pragma unroll
      for (int r = 0; r < 4; r++) acc[mi][ni][r] = 0.0f;

  auto stage = [&](int bi, int kt) {
#pragma unroll
    for (int i = 0; i < LA; ++i) {
      const int j = LA * w + i;
      gld_lds16(&sA[bi][j * 512],
                A + (size_t)(bm0 + j * 16 + srow) * K + (size_t)kt * 32 + csel);
    }
#pragma unroll
    for (int i = 0; i < 2; ++i) {
      const int j = 2 * w + i;
      gld_lds16(&sB[bi][j * 512],
                Bt + (size_t)(bn0 + j * 16 + srow) * K + (size_t)kt * 32 + csel);
    }
  };

  stage(0, 0);
  __syncthreads();
  const int KT = K >> 5;
#pragma unroll 1
  for (int kt = 0; kt < KT; ++kt) {
    const int cur = kt & 1;
    if (kt + 1 < KT) stage(cur ^ 1, kt + 1);
    half8 a[MF], b[4];
#pragma unroll
    for (int mi = 0; mi < MF; mi++)
      a[mi] = *(const half8*)&sA[cur][(wm * (BM / 2) + mi * 16 + lo) * 32 + kswz];
#pragma unroll
    for (int ni = 0; ni < 4; ni++)
      b[ni] = *(const half8*)&sB[cur][(wn * 64 + ni * 16 + lo) * 32 + kswz];
#pragma unroll
    for (int mi = 0; mi < MF; mi++)
#pragma unroll
      for (int ni = 0; ni < 4; ni++)
        acc[mi][ni] = __builtin_amdgcn_mfma_f32_16x16x32_f16(a[mi], b[ni], acc[mi][ni], 0, 0, 0);
    __syncthreads();
  }

#pragma unroll
  for (int mi = 0; mi < MF; mi++)
#pragma unroll
    for (int ni = 0; ni < 4; ni++)
#pragma unroll
      for (int r = 0; r < 4; r++) {
        const size_t idx = (size_t)(bm0 + wm * (BM / 2) + mi * 16 + hi * 4 + r) * N +
                           (bn0 + wn * 64 + ni * 16 + lo);
        if constexpr (F16OUT) ((_Float16*)Cv)[idx] = (_Float16)acc[mi][ni][r];
        else                  ((float*)Cv)[idx] = acc[mi][ni][r];
      }
}

// ---------------- fused RMSNorm+RoPE (Q,K) + V transpose, one launch --------------
// QKV now f16 [4096][4096] (written full-line by gemm256).
__global__ __launch_bounds__(256) void post(const _Float16* __restrict__ QKV,
                                            const int* __restrict__ pos,
                                            const float* __restrict__ qw,
                                            const float* __restrict__ kw,
                                            _Float16* __restrict__ Qb,
                                            _Float16* __restrict__ Kb,
                                            _Float16* __restrict__ Vt) {
  if (blockIdx.x >= 24576) {
    __shared__ _Float16 tt[32][34];  // stride 68B: 17 dwords (odd) -> conflict-free col reads
    const int g = blockIdx.x - 24576;
    const int tx = threadIdx.x & 31, ty = threadIdx.x >> 5;
    const int dt = g & 3;
    const int st = (g >> 2) & 63;
    const int bh = g >> 8;
    const _Float16* src = QKV + (size_t)((bh >> 3) * 2048 + st * 32) * 4096 +
                          3072 + (bh & 7) * 128 + dt * 32;
#pragma unroll
    for (int i = 0; i < 4; i++)
      tt[ty + 8 * i][tx] = src[(size_t)(ty + 8 * i) * 4096 + tx];
    __syncthreads();
    _Float16* dst = Vt + ((size_t)bh * 128 + dt * 32) * 2048 + st * 32;
#pragma unroll
    for (int i = 0; i < 4; i++) {
      const int rr = ty + 8 * i;
      dst[(size_t)rr * 2048 + tx] = tt[tx][rr];
    }
    return;
  }
  const int w = threadIdx.x >> 6, l = threadIdx.x & 63;
  const int wv = blockIdx.x * 4 + w;
  const int t = wv / 24, hh = wv - t * 24;
  const int b = t >> 11, s = t & 2047;
  const bool isq = hh < 16;
  const int col = isq ? hh * 128 : 2048 + (hh - 16) * 128;
  const _Float16* x = QKV + (size_t)t * 4096 + col;
  const float x1 = (float)x[l], x2 = (float)x[l + 64];
  float ss = x1 * x1 + x2 * x2;
  ss += __shfl_xor(ss, 32); ss += __shfl_xor(ss, 16); ss += __shfl_xor(ss, 8);
  ss += __shfl_xor(ss, 4);  ss += __shfl_xor(ss, 2);  ss += __shfl_xor(ss, 1);
  const float rn = rsqrtf(ss * 0.0078125f + 1e-6f);
  const float* wt = isq ? qw : kw;
  const float n1 = x1 * rn * wt[l], n2 = x2 * rn * wt[l + 64];
  const float ang = (float)pos[s] * exp2f((float)l * -0.2076205059304601f);
  float sa, ca;
  sincosf(ang, &sa, &ca);
  const float qs = isq ? 0.12751731f : 1.0f;  // SCALE * log2(e), Q only
  const float o1 = (n1 * ca - n2 * sa) * qs;
  const float o2 = (n2 * ca + n1 * sa) * qs;
  _Float16* dst = isq ? Qb + (((size_t)b * 16 + hh) * 2048 + s) * 128
                      : Kb + (((size_t)b * 8 + (hh - 16)) * 2048 + s) * 128;
  dst[l] = (_Float16)o1;
  dst[l + 64] = (_Float16)o2;
}

// ---------------- causal GQA flash attention (R14-proven, P stride 72) -------------
__global__ __launch_bounds__(256) void attn_fwd(const _Float16* __restrict__ Q,
                                                const _Float16* __restrict__ K,
                                                const _Float16* __restrict__ Vt,
                                                _Float16* __restrict__ AO) {
  __shared__ _Float16 sK[2][64 * 128];   // 16 KB per buffer
  __shared__ _Float16 sV[2][128 * 64];   // 16 KB per buffer
  __shared__ _Float16 P[4][16 * 72];     // per-wave P tile, stride 72
  const int tid = threadIdx.x, w = tid >> 6, l = tid & 63, lo = l & 15, hi = l >> 4;
  const int qt = 31 - (blockIdx.x >> 5);  // heavy-first launch order
  const int hq = blockIdx.x & 15;
  const int b = (blockIdx.x >> 4) & 1;
  const int hk = hq >> 1, q0 = qt * 64;
  const _Float16* Qh = Q + ((size_t)(b * 16 + hq) * 2048) * 128;
  const _Float16* Kh = K + ((size_t)(b * 8 + hk) * 2048) * 128;
  const _Float16* Vh = Vt + ((size_t)(b * 8 + hk) * 128) * 2048;
  const int qw0 = q0 + w * 16;

  auto stageK = [&](int bi, int kv0) {
#pragma unroll
    for (int i = 0; i < 4; ++i) {
      const int inst = w * 4 + i;
      const int r = inst * 4 + (l >> 4);
      const int cb = ((l & 15) * 16) ^ ((r & 7) << 4);
      gld_lds16(&sK[bi][inst * 512],
                (const char*)Kh + (size_t)(kv0 + r) * 256 + cb);
    }
  };
  auto stageV = [&](int bi, int kv0) {
#pragma unroll
    for (int i = 0; i < 4; ++i) {
      const int inst = w * 4 + i;
      const int r = inst * 8 + (l >> 3);
      const int cb = ((l & 7) * 16) ^ ((r & 7) << 4);
      gld_lds16(&sV[bi][inst * 512],
                (const char*)Vh + (size_t)r * 4096 + (size_t)kv0 * 2 + cb);
    }
  };

  half8 aq[4];
#pragma unroll
  for (int kc = 0; kc < 4; kc++)
    aq[kc] = *(const half8*)(Qh + (size_t)(qw0 + lo) * 128 + kc * 32 + hi * 8);

  f32x4 o[8];
#pragma unroll
  for (int dn = 0; dn < 8; dn++)
#pragma unroll
    for (int r = 0; r < 4; r++) o[dn][r] = 0.0f;
  float mrow = -1e30f, lrow = 0.0f;

  const int nt = qt + 1;
  stageK(0, 0);
  stageV(0, 0);
  __syncthreads();
#pragma unroll 1
  for (int kt = 0; kt < nt; ++kt) {
    const int kv0 = kt * 64;
    const int cur = kt & 1;
    if (kt + 1 < nt) {
      stageK(cur ^ 1, kv0 + 64);
      stageV(cur ^ 1, kv0 + 64);
    }
    const char* kb = (const char*)sK[cur];
    const char* vb = (const char*)sV[cur];
    f32x4 s[4];
#pragma unroll
    for (int ns = 0; ns < 4; ns++) {
#pragma unroll
      for (int r = 0; r < 4; r++) s[ns][r] = 0.0f;
      const int krow = ns * 16 + lo;
#pragma unroll
      for (int kc = 0; kc < 4; kc++) {
        half8 bk = *(const half8*)(kb + krow * 256 +
                                   ((kc * 64 + hi * 16) ^ ((krow & 7) << 4)));
        s[ns] = __builtin_amdgcn_mfma_f32_16x16x32_f16(bk, aq[kc], s[ns], 0, 0, 0);
      }
    }
    if (kt == nt - 1) {
#pragma unroll
      for (int ns = 0; ns < 4; ns++) {
        const int kv = kv0 + ns * 16 + hi * 4;
#pragma unroll
        for (int r = 0; r < 4; r++)
          if (kv + r > qw0 + lo) s[ns][r] = -1e30f;
      }
    }
    float tmax = s[0][0];
#pragma unroll
    for (int ns = 0; ns < 4; ns++)
#pragma unroll
      for (int r = 0; r < 4; r++) tmax = fmaxf(tmax, s[ns][r]);
    tmax = fmaxf(tmax, __shfl_xor(tmax, 16));
    tmax = fmaxf(tmax, __shfl_xor(tmax, 32));
    if (!__all(tmax <= mrow + 8.0f)) {
      const float mn = fmaxf(mrow, tmax);
      const float corr = exp2f(mrow - mn);
      mrow = mn;
      lrow *= corr;
      float c4[4];
#pragma unroll
      for (int r = 0; r < 4; r++) c4[r] = __shfl(corr, hi * 4 + r, 16);
#pragma unroll
      for (int dn = 0; dn < 8; dn++)
#pragma unroll
        for (int r = 0; r < 4; r++) o[dn][r] *= c4[r];
    }
    float psum = 0.0f;
#pragma unroll
    for (int ns = 0; ns < 4; ns++) {
      half4 pk;
#pragma unroll
      for (int r = 0; r < 4; r++) {
        const float p = exp2f(s[ns][r] - mrow);
        psum += p;
        pk[r] = (_Float16)p;
      }
      *(half4*)&P[w][lo * 72 + ns * 16 + hi * 4] = pk;
    }
    psum += __shfl_xor(psum, 16);
    psum += __shfl_xor(psum, 32);
    lrow += psum;
    asm volatile("s_waitcnt lgkmcnt(0)" ::: "memory");
    half8 ap0 = *(const half8*)&P[w][lo * 72 + hi * 8];
    half8 ap1 = *(const half8*)&P[w][lo * 72 + 32 + hi * 8];
#pragma unroll
    for (int dn = 0; dn < 8; dn++) {
      const int vrow = dn * 16 + lo;
      half8 bv0 = *(const half8*)(vb + vrow * 128 + ((hi * 16) ^ ((vrow & 7) << 4)));
      half8 bv1 = *(const half8*)(vb + vrow * 128 + ((64 + hi * 16) ^ ((vrow & 7) << 4)));
      o[dn] = __builtin_amdgcn_mfma_f32_16x16x32_f16(ap0, bv0, o[dn], 0, 0, 0);
      o[dn] = __builtin_amdgcn_mfma_f32_16x16x32_f16(ap1, bv1, o[dn], 0, 0, 0);
    }
    __syncthreads();
  }

  const float inv = 1.0f / lrow;
  float i4[4];
#pragma unroll
  for (int r = 0; r < 4; r++) i4[r] = __shfl(inv, hi * 4 + r, 16);
  const size_t tok = (size_t)b * 2048 + qw0;
#pragma unroll
  for (int dn = 0; dn < 8; dn++)
#pragma unroll
    for (int r = 0; r < 4; r++)
      AO[(tok + hi * 4 + r) * 2048 + hq * 128 + dn * 16 + lo] = (_Float16)(o[dn][r] * i4[r]);
}

// ---------------- launch ----------------
extern "C" void kernel_launch(void* const* d_in, const int* in_sizes, int n_in,
                              void* d_out, int out_size, void* d_ws, size_t ws_size,
                              hipStream_t stream) {
  (void)in_sizes; (void)n_in; (void)out_size; (void)ws_size;
  const float* hs  = (const float*)d_in[0];
  const int*   pos = (const int*)d_in[1];
  const float* Wq  = (const float*)d_in[2];
  const float* Wk  = (const float*)d_in[3];
  const float* Wv  = (const float*)d_in[4];
  const float* Wo  = (const float*)d_in[5];
  const float* qnw = (const float*)d_in[6];
  const float* knw = (const float*)d_in[7];
  float* out = (float*)d_out;

  char* ws = (char*)d_ws;
  size_t off = 0;
  auto take = [&](size_t bytes) -> void* {
    void* p = ws + off;
    off += (bytes + 255) & ~(size_t)255;
    return p;
  };
  _Float16* Xh    = (_Float16*)take((size_t)4096 * 2048 * 2);   // hidden f16
  _Float16* Wqkvt = (_Float16*)take((size_t)4096 * 2048 * 2);   // packed [Wq;Wk;Wv]^T
  _Float16* Wot   = (_Float16*)take((size_t)2048 * 2048 * 2);   // Wo^T
  _Float16* QKVh  = (_Float16*)take((size_t)4096 * 4096 * 2);   // projection out f16
  _Float16* Qb    = (_Float16*)take((size_t)2 * 16 * 2048 * 128 * 2);
  _Float16* Kb    = (_Float16*)take((size_t)2 * 8 * 2048 * 128 * 2);
  _Float16* Vt    = (_Float16*)take((size_t)2 * 8 * 128 * 2048 * 2);
  _Float16* AO    = (_Float16*)take((size_t)4096 * 2048 * 2);   // attention out f16

  prep<<<16384, 256, 0, stream>>>(hs, Wq, Wk, Wv, Wo, Xh, Wqkvt, Wot);
  gemm256<<<256, 512, 0, stream>>>(Xh, Wqkvt, QKVh, 4096, 4096, 2048);
  post<<<28672, 256, 0, stream>>>(QKVh, pos, qnw, knw, Qb, Kb, Vt);
  attn_fwd<<<1024, 256, 0, stream>>>(Qb, Kb, Vt, AO);
  gemm_bt<64, false><<<dim3(16, 64), 256, 0, stream>>>(AO, Wot, out, 4096, 2048, 2048);
}